// Round 1
// baseline (1424.345 us; speedup 1.0000x reference)
//
#include <hip/hip_runtime.h>
#include <math.h>

#define NPTS 8192
#define NPS  (NPTS*32)

__device__ __forceinline__ float tanh_fast(float x) {
  float e = __expf(2.0f*x);
  return 1.0f - 2.0f*__builtin_amdgcn_rcpf(e + 1.0f);
}

// ---------------- prologue kernels ----------------

// A = softmax(relu(gE @ gE^T), axis=1)   (512x512), one block per row
__global__ void kA_softmax(const float* __restrict__ gE, float* __restrict__ A) {
  __shared__ float gn[16];
  __shared__ float red[256];
  int n = blockIdx.x, t = threadIdx.x;
  if (t < 16) gn[t] = gE[n*16 + t];
  __syncthreads();
  float e0, e1;
  {
    float d = 0.f;
    #pragma unroll
    for (int dd = 0; dd < 16; ++dd) d = fmaf(gn[dd], gE[t*16 + dd], d);
    e0 = __expf(fmaxf(d, 0.f));
  }
  {
    float d = 0.f;
    #pragma unroll
    for (int dd = 0; dd < 16; ++dd) d = fmaf(gn[dd], gE[(t+256)*16 + dd], d);
    e1 = __expf(fmaxf(d, 0.f));
  }
  red[t] = e0 + e1;
  __syncthreads();
  for (int off = 128; off > 0; off >>= 1) {
    if (t < off) red[t] += red[t+off];
    __syncthreads();
  }
  float inv = __builtin_amdgcn_rcpf(red[0]);
  A[n*512 + t]       = e0*inv;
  A[n*512 + t + 256] = e1*inv;
}

// aw[n][k][i][o] = sum_d gE[n][d]*gWpool[d][k][i][o];  ab[n][o] = sum_d gE[n][d]*gbpool[d][o]
__global__ void kAwAb(const float* __restrict__ gE, const float* __restrict__ gWpool,
                      const float* __restrict__ gbpool, float* __restrict__ aw,
                      float* __restrict__ ab) {
  __shared__ float gn[16];
  int n = blockIdx.x, t = threadIdx.x;
  if (t < 16) gn[t] = gE[n*16 + t];
  __syncthreads();
  for (int e = t; e < 2048; e += 256) {
    float s = 0.f;
    #pragma unroll
    for (int d = 0; d < 16; ++d) s = fmaf(gn[d], gWpool[d*2048 + e], s);
    aw[n*2048 + e] = s;
  }
  if (t < 32) {
    float s = 0.f;
    #pragma unroll
    for (int d = 0; d < 16; ++d) s = fmaf(gn[d], gbpool[d*32 + t], s);
    ab[n*32 + t] = s;
  }
}

// dX[slot][p][i]: slot 0 = (t-idx 0, frac 0); slot 1+3k+j = (t-idx k, frac (j+1)/3)
__global__ void kDX(const float* __restrict__ cb, const float* __restrict__ cc2,
                    const float* __restrict__ cd3, float* __restrict__ dX) {
  int idx = blockIdx.x*256 + threadIdx.x;       // 34*16384 = 557056 total
  int slot = idx >> 14;
  int rem = idx & 16383;
  int p = rem >> 1, i = rem & 1;
  float v;
  if (slot == 0) {
    v = cb[p*22 + i];
  } else {
    int s1 = slot - 1;
    int k = s1 / 3, j = s1 - 3*k;
    float frac = (float)(j+1) * (1.0f/3.0f);
    if (j == 2) frac = 1.0f;
    int base = p*22 + k*2 + i;
    v = cb[base] + (cc2[base] + cd3[base]*frac)*frac;
  }
  dX[idx] = v;
}

// h0 = x0@Wh + bh ; z0 = x0@Wz + bz with x0 = coeff_a[:,:,0,:]
__global__ void kInit(const float* __restrict__ ca, const float* __restrict__ Wh,
                      const float* __restrict__ bh, const float* __restrict__ Wz,
                      const float* __restrict__ bz, float* __restrict__ h,
                      float* __restrict__ z) {
  int idx = blockIdx.x*256 + threadIdx.x;       // 262144
  int c = idx & 31, p = idx >> 5;
  float x0 = ca[p*22 + 0], x1 = ca[p*22 + 1];
  h[idx] = fmaf(x0, Wh[c], fmaf(x1, Wh[32+c], bh[c]));
  z[idx] = fmaf(x0, Wz[c], fmaf(x1, Wz[32+c], bz[c]));
}

// initial xrel = relu(z @ gWin + gbin); 8 points per 256-thread block
__global__ void kXrel0(const float* __restrict__ z, const float* __restrict__ gWin,
                       const float* __restrict__ gbin, float* __restrict__ xrel) {
  __shared__ float zl[8][32];
  int t = threadIdx.x, pl = t >> 5, c = t & 31;
  int p = blockIdx.x*8 + pl;
  zl[pl][c] = z[p*32 + c];
  __syncthreads();
  float s = gbin[c];
  #pragma unroll
  for (int i = 0; i < 32; ++i) s = fmaf(zl[pl][i], gWin[i*32 + c], s);
  xrel[p*32 + c] = fmaxf(s, 0.f);
}

// ---------------- per-stage kernels ----------------

// agg[b][n][c] = sum_m A[n][m] * xrel[b][m][c]
// grid 256 = (b 16) x (32-row tile 16); 256 threads; 4x4 register tile, 4-way m-split
__global__ __launch_bounds__(256) void kAgg(const float* __restrict__ A,
                                            const float* __restrict__ xrel,
                                            float* __restrict__ agg) {
  __shared__ __align__(16) float xt[64][32];
  __shared__ float At[32][65];
  __shared__ float part[4][32][32];
  int bid = blockIdx.x;
  int b = bid >> 4, tl = bid & 15, n0 = tl*32;
  int t = threadIdx.x;
  int mpart = t >> 6;            // 0..3
  int slot = t & 63;
  int rq = slot >> 3, cq = slot & 7;   // 8x8 slots, 4 rows x 4 cols each
  float acc[4][4] = {{0.f}};
  for (int mt = 0; mt < 8; ++mt) {
    __syncthreads();
    #pragma unroll
    for (int j = 0; j < 8; ++j) {
      int idx = t + j*256;
      xt[idx>>5][idx&31] = xrel[(b*512 + mt*64 + (idx>>5))*32 + (idx&31)];
    }
    #pragma unroll
    for (int j = 0; j < 8; ++j) {
      int idx = t + j*256;
      At[idx>>6][idx&63] = A[(n0 + (idx>>6))*512 + mt*64 + (idx&63)];
    }
    __syncthreads();
    #pragma unroll
    for (int mi = 0; mi < 16; ++mi) {
      int mm = mpart*16 + mi;
      float xv[4], av[4];
      #pragma unroll
      for (int e = 0; e < 4; ++e) xv[e] = xt[mm][cq*4+e];
      #pragma unroll
      for (int e = 0; e < 4; ++e) av[e] = At[rq*4+e][mm];
      #pragma unroll
      for (int r = 0; r < 4; ++r)
        #pragma unroll
        for (int c = 0; c < 4; ++c) acc[r][c] = fmaf(av[r], xv[c], acc[r][c]);
    }
  }
  #pragma unroll
  for (int r = 0; r < 4; ++r)
    #pragma unroll
    for (int c = 0; c < 4; ++c) part[mpart][rq*4+r][cq*4+c] = acc[r][c];
  __syncthreads();
  #pragma unroll
  for (int j = 0; j < 4; ++j) {
    int idx = t + j*256;
    int r = idx >> 5, c = idx & 31;
    float s = (part[0][r][c] + part[1][r][c]) + (part[2][r][c] + part[3][r][c]);
    agg[(b*512 + n0 + r)*32 + c] = s;
  }
}

// Fused per-stage kernel: pooled einsum, func_f, dh, gWout GEMM + tanh + dz,
// RK bookkeeping, and next-stage xrel. 512 threads, 16 points/block, 512 blocks.
__global__ __launch_bounds__(512) void kBF(
    const float* __restrict__ aw, const float* __restrict__ ab,
    const float* __restrict__ dX, float* __restrict__ h, float* __restrict__ z,
    float* __restrict__ kh, float* __restrict__ kz,
    float* __restrict__ xrel, const float* __restrict__ agg,
    const float* __restrict__ fWin, const float* __restrict__ fbin,
    const float* __restrict__ fWmid, const float* __restrict__ fbmid,
    const float* __restrict__ fWout, const float* __restrict__ fbout,
    const float* __restrict__ gWin, const float* __restrict__ gbin,
    const float* __restrict__ gWout, const float* __restrict__ gbout,
    int stage, int slot)
{
  __shared__ __align__(16) float gW_l[32*256];   // 32KB gWout col-tile
  __shared__ float XR[16][32], AG[16][32], PL[16][32], HS[16][32];
  __shared__ float X1[16][32], X2[16][32], DH[16][32], DZ[16][32];
  __shared__ float wIn[1024], wMid[1024], wOut[2048], wG[1024];
  __shared__ float bIn[32], bMid[32], bOut[64], bG[32], bGout[1024];
  __shared__ float scr[1024];

  int t = threadIdx.x;
  int pl = t >> 5, o = t & 31;
  int pg = blockIdx.x*16 + pl;     // global point
  int n = pg & 511;

  // phase 0: stage weights/biases, load xrel/agg, build stage-input h_s
  for (int j = t; j < 1024; j += 512) wIn[j] = fWin[j];
  for (int j = t; j < 1024; j += 512) wMid[j] = fWmid[j];
  for (int j = t; j < 2048; j += 512) wOut[j] = fWout[j];
  for (int j = t; j < 1024; j += 512) wG[j] = gWin[j];
  for (int j = t; j < 1024; j += 512) bGout[j] = gbout[j];
  if (t < 32) bIn[t] = fbin[t];
  else if (t >= 64 && t < 96) bMid[t-64] = fbmid[t-64];
  else if (t >= 128 && t < 192) bOut[t-128] = fbout[t-128];
  else if (t >= 256 && t < 288) bG[t-256] = gbin[t-256];

  XR[pl][o] = xrel[pg*32 + o];
  AG[pl][o] = agg[pg*32 + o];
  {
    float hv = h[pg*32 + o];
    float hsv;
    if (stage == 1)      hsv = hv;
    else if (stage == 2) hsv = fmaf(kh[pg*32+o], (1.f/3.f), hv);
    else if (stage == 3) hsv = hv - (1.f/3.f)*kh[pg*32+o] + kh[NPS + pg*32+o];
    else                 hsv = hv + kh[pg*32+o] - kh[NPS + pg*32+o] + kh[2*NPS + pg*32+o];
    HS[pl][o] = hsv;
  }
  __syncthreads();

  // phase 1a: pooled einsum + first f-layer
  {
    const float* awp = aw + n*2048;
    float s = ab[n*32 + o];
    #pragma unroll
    for (int i = 0; i < 32; ++i) {
      s = fmaf(XR[pl][i], awp[i*32 + o], s);
      s = fmaf(AG[pl][i], awp[1024 + i*32 + o], s);
    }
    PL[pl][o] = s;
  }
  {
    float s = bIn[o];
    #pragma unroll
    for (int i = 0; i < 32; ++i) s = fmaf(HS[pl][i], wIn[i*32 + o], s);
    X1[pl][o] = fmaxf(s, 0.f);
  }
  __syncthreads();
  {
    float s = bMid[o];
    #pragma unroll
    for (int i = 0; i < 32; ++i) s = fmaf(X1[pl][i], wMid[i*32 + o], s);
    X2[pl][o] = fmaxf(s, 0.f);
  }
  __syncthreads();
  // phase 1b: vf, dh, RK-h bookkeeping
  {
    float s0 = bOut[2*o], s1 = bOut[2*o + 1];
    #pragma unroll
    for (int i = 0; i < 32; ++i) {
      float xv = X2[pl][i];
      s0 = fmaf(xv, wOut[i*64 + 2*o], s0);
      s1 = fmaf(xv, wOut[i*64 + 2*o + 1], s1);
    }
    float vf0 = tanh_fast(s0), vf1 = tanh_fast(s1);
    float dx0 = dX[slot*16384 + pg*2], dx1 = dX[slot*16384 + pg*2 + 1];
    float dhv = fmaf(vf0, dx0, vf1*dx1);
    DH[pl][o] = dhv;
    if (stage < 4) {
      kh[(stage-1)*NPS + pg*32 + o] = dhv;
    } else {
      float hv = h[pg*32+o];
      float k1 = kh[pg*32+o], k2 = kh[NPS+pg*32+o], k3 = kh[2*NPS+pg*32+o];
      h[pg*32+o] = hv + 0.125f*(k1 + 3.f*(k2 + k3) + dhv);
    }
  }
  __syncthreads();

  // phase 2: dz[p][hh] = sum_o tanh(PL@gWout + gbout)[hh*32+o] * DH[p][o]
  {
    int quad = t & 63;            // 64 col-quads per 256-col tile
    int og = quad & 7, hq = quad >> 3;
    int pgrp = t >> 6;            // wave-uniform
    int pA = pgrp*2, pB = pA + 1;
    const float4* gw4 = (const float4*)gW_l;
    for (int jt = 0; jt < 4; ++jt) {
      #pragma unroll
      for (int q = 0; q < 4; ++q) {
        int idx = t + q*512;
        int i = idx >> 6, jj4 = idx & 63;
        *(float4*)&gW_l[i*256 + jj4*4] =
            *(const float4*)&gWout[i*1024 + jt*256 + jj4*4];
      }
      __syncthreads();
      float4 y0 = {0,0,0,0}, y1 = {0,0,0,0};
      #pragma unroll
      for (int i = 0; i < 32; ++i) {
        float4 g = gw4[i*64 + quad];
        float a0 = PL[pA][i], a1 = PL[pB][i];
        y0.x = fmaf(a0, g.x, y0.x); y0.y = fmaf(a0, g.y, y0.y);
        y0.z = fmaf(a0, g.z, y0.z); y0.w = fmaf(a0, g.w, y0.w);
        y1.x = fmaf(a1, g.x, y1.x); y1.y = fmaf(a1, g.y, y1.y);
        y1.z = fmaf(a1, g.z, y1.z); y1.w = fmaf(a1, g.w, y1.w);
      }
      int hh = jt*8 + hq, ob = og*4;
      float ya[4] = {y0.x, y0.y, y0.z, y0.w};
      float yb[4] = {y1.x, y1.y, y1.z, y1.w};
      float c0 = 0.f, c1 = 0.f;
      #pragma unroll
      for (int e = 0; e < 4; ++e) {
        float gb = bGout[hh*32 + ob + e];
        c0 = fmaf(tanh_fast(ya[e] + gb), DH[pA][ob+e], c0);
        c1 = fmaf(tanh_fast(yb[e] + gb), DH[pB][ob+e], c1);
      }
      scr[pA*64 + quad] = c0;
      scr[pB*64 + quad] = c1;
      __syncthreads();
      if (t < 128) {
        int pp = t >> 3, hq2 = t & 7;
        float s = 0.f;
        #pragma unroll
        for (int g2 = 0; g2 < 8; ++g2) s += scr[pp*64 + hq2*8 + g2];
        DZ[pp][jt*8 + hq2] = s;
      }
      __syncthreads();
    }
  }

  // phase 3: RK-z bookkeeping + next-stage z
  {
    float dzv = DZ[pl][o];
    float zv = z[pg*32 + o];
    float znv;
    if (stage == 1) {
      kz[pg*32+o] = dzv;
      znv = fmaf(dzv, (1.f/3.f), zv);
    } else if (stage == 2) {
      kz[NPS + pg*32+o] = dzv;
      znv = zv - (1.f/3.f)*kz[pg*32+o] + dzv;
    } else if (stage == 3) {
      kz[2*NPS + pg*32+o] = dzv;
      znv = zv + kz[pg*32+o] - kz[NPS+pg*32+o] + dzv;
    } else {
      float k1 = kz[pg*32+o], k2 = kz[NPS+pg*32+o], k3 = kz[2*NPS+pg*32+o];
      znv = zv + 0.125f*(k1 + 3.f*(k2 + k3) + dzv);
      z[pg*32+o] = znv;
    }
    HS[pl][o] = znv;   // reuse HS as next-z
  }
  __syncthreads();
  // phase 4: next xrel = relu(z_next @ gWin + gbin)
  {
    float s = bG[o];
    #pragma unroll
    for (int i = 0; i < 32; ++i) s = fmaf(HS[pl][i], wG[i*32 + o], s);
    xrel[pg*32 + o] = fmaxf(s, 0.f);
  }
}

// out[b,0,n,o] = sum_h z[b,n,h]*convW[o,h] + convb[o]
__global__ void kOut(const float* __restrict__ z, const float* __restrict__ convW,
                     const float* __restrict__ convb, float* __restrict__ out) {
  int idx = blockIdx.x*256 + threadIdx.x;   // 98304
  int o = idx % 12, p = idx / 12;
  float s = convb[o];
  #pragma unroll
  for (int hh = 0; hh < 32; ++hh) s = fmaf(z[p*32 + hh], convW[o*32 + hh], s);
  out[idx] = s;
}

extern "C" void kernel_launch(void* const* d_in, const int* in_sizes, int n_in,
                              void* d_out, int out_size, void* d_ws, size_t ws_size,
                              hipStream_t stream) {
  (void)in_sizes; (void)n_in; (void)out_size; (void)ws_size;
  const float* ca     = (const float*)d_in[1];
  const float* cb     = (const float*)d_in[2];
  const float* cc2    = (const float*)d_in[3];
  const float* cd3    = (const float*)d_in[4];
  const float* Wh     = (const float*)d_in[5];
  const float* bh     = (const float*)d_in[6];
  const float* Wz     = (const float*)d_in[7];
  const float* bz     = (const float*)d_in[8];
  const float* fWin   = (const float*)d_in[9];
  const float* fbin   = (const float*)d_in[10];
  const float* fWmid  = (const float*)d_in[11];
  const float* fbmid  = (const float*)d_in[12];
  const float* fWout  = (const float*)d_in[13];
  const float* fbout  = (const float*)d_in[14];
  const float* gWin   = (const float*)d_in[15];
  const float* gbin   = (const float*)d_in[16];
  const float* gE     = (const float*)d_in[17];
  const float* gWpool = (const float*)d_in[18];
  const float* gbpool = (const float*)d_in[19];
  const float* gWout  = (const float*)d_in[20];
  const float* gbout  = (const float*)d_in[21];
  const float* convW  = (const float*)d_in[22];
  const float* convb  = (const float*)d_in[23];
  float* out = (float*)d_out;

  float* wsf   = (float*)d_ws;
  float* wA    = wsf;                  // 262144
  float* wAw   = wA + 262144;          // 1048576
  float* wAb   = wAw + 1048576;        // 16384
  float* wDX   = wAb + 16384;          // 557056
  float* wH    = wDX + 557056;         // NPS
  float* wZ    = wH + NPS;             // NPS
  float* wKh   = wZ + NPS;             // 3*NPS
  float* wKz   = wKh + 3*NPS;          // 3*NPS
  float* wXrel = wKz + 3*NPS;          // NPS
  float* wAgg  = wXrel + NPS;          // NPS

  kA_softmax<<<512, 256, 0, stream>>>(gE, wA);
  kAwAb<<<512, 256, 0, stream>>>(gE, gWpool, gbpool, wAw, wAb);
  kDX<<<2176, 256, 0, stream>>>(cb, cc2, cd3, wDX);
  kInit<<<1024, 256, 0, stream>>>(ca, Wh, bh, Wz, bz, wH, wZ);
  kXrel0<<<1024, 256, 0, stream>>>(wZ, gWin, gbin, wXrel);

  for (int step = 0; step < 11; ++step) {
    for (int s = 1; s <= 4; ++s) {
      int slot = (step == 0 && s == 1) ? 0 : (3*step + (s-1));
      kAgg<<<256, 256, 0, stream>>>(wA, wXrel, wAgg);
      kBF<<<512, 512, 0, stream>>>(wAw, wAb, wDX, wH, wZ, wKh, wKz, wXrel, wAgg,
                                   fWin, fbin, fWmid, fbmid, fWout, fbout,
                                   gWin, gbin, gWout, gbout, s, slot);
    }
  }
  kOut<<<384, 256, 0, stream>>>(wZ, convW, convb, out);
}

// Round 2
// 1033.858 us; speedup vs baseline: 1.3777x; 1.3777x over previous
//
#include <hip/hip_runtime.h>
#include <math.h>

#define NPTS 8192
#define NPS  (NPTS*32)

typedef __attribute__((ext_vector_type(8))) short bf16x8;
typedef __attribute__((ext_vector_type(4))) float f32x4;

__device__ __forceinline__ float tanh_fast(float x) {
  float e = __expf(2.0f*x);
  return 1.0f - 2.0f*__builtin_amdgcn_rcpf(e + 1.0f);
}
__device__ __forceinline__ unsigned short bf16h(float x) {
  unsigned u = __float_as_uint(x);
  return (unsigned short)((u + 0x7FFFu + ((u>>16)&1u)) >> 16);
}
__device__ __forceinline__ float bf16f(unsigned short h) {
  return __uint_as_float(((unsigned)h)<<16);
}

// ---------------- prologue kernels ----------------

// A = softmax(relu(gE@gE^T)) row n; write packed bf16 hi/lo A-fragments directly.
// A-frag (M=16,K=32 chunk c, tile nt): lane l elem j = A[nt*16+(l&15)][c*32+(l>>4)*8+j]
__global__ void kA_softmax(const float* __restrict__ gE, short* __restrict__ ApkH,
                           short* __restrict__ ApkL) {
  __shared__ float gn[16];
  __shared__ float red[256];
  int n = blockIdx.x, t = threadIdx.x;
  if (t < 16) gn[t] = gE[n*16 + t];
  __syncthreads();
  float e0, e1;
  {
    float d = 0.f;
    #pragma unroll
    for (int dd = 0; dd < 16; ++dd) d = fmaf(gn[dd], gE[t*16 + dd], d);
    e0 = __expf(fmaxf(d, 0.f));
  }
  {
    float d = 0.f;
    #pragma unroll
    for (int dd = 0; dd < 16; ++dd) d = fmaf(gn[dd], gE[(t+256)*16 + dd], d);
    e1 = __expf(fmaxf(d, 0.f));
  }
  red[t] = e0 + e1;
  __syncthreads();
  for (int off = 128; off > 0; off >>= 1) {
    if (t < off) red[t] += red[t+off];
    __syncthreads();
  }
  float inv = __builtin_amdgcn_rcpf(red[0]);
  int nt = n >> 4;
  #pragma unroll
  for (int half = 0; half < 2; ++half) {
    int k = t + half*256;
    float v = (half ? e1 : e0) * inv;
    int c = k >> 5, g = (k>>3)&3, j = k&7;
    int l = g*16 + (n&15);
    size_t off2 = ((size_t)(nt*16 + c)*64 + l)*8 + j;
    unsigned short hb = bf16h(v);
    ApkH[off2] = (short)hb;
    ApkL[off2] = (short)bf16h(v - bf16f(hb));
  }
}

// awT[n][o][ii] = sum_d gE[n][d]*gWpool[d][k][i][o] (ii=k*32+i); ab[n][o]
__global__ void kAwT(const float* __restrict__ gE, const float* __restrict__ gWpool,
                     const float* __restrict__ gbpool, float* __restrict__ awT,
                     float* __restrict__ ab) {
  __shared__ float gn[16];
  int n = blockIdx.x, t = threadIdx.x;
  if (t < 16) gn[t] = gE[n*16 + t];
  __syncthreads();
  for (int e = t; e < 2048; e += 256) {
    int o = e >> 6, ii = e & 63;
    int k = ii >> 5, i = ii & 31;
    float s = 0.f;
    #pragma unroll
    for (int d = 0; d < 16; ++d) s = fmaf(gn[d], gWpool[d*2048 + k*1024 + i*32 + o], s);
    awT[((size_t)n*32 + o)*64 + ii] = s;
  }
  if (t < 32) {
    float s = 0.f;
    #pragma unroll
    for (int d = 0; d < 16; ++d) s = fmaf(gn[d], gbpool[d*32 + t], s);
    ab[n*32 + t] = s;
  }
}

// gWout (32x1024) -> packed bf16 hi/lo B-fragments.
// B-frag tile tl: lane l elem j = B[(l>>4)*8+j][tl*16+(l&15)]
__global__ void kPackGW(const float* __restrict__ gWout, short* __restrict__ GpkH,
                        short* __restrict__ GpkL) {
  int idx = blockIdx.x*256 + threadIdx.x;   // 32768
  int j = idx & 7, l = (idx>>3)&63, tl = idx>>9;
  int col = tl*16 + (l&15);
  int k = ((l>>4)&3)*8 + j;
  float v = gWout[k*1024 + col];
  unsigned short hb = bf16h(v);
  GpkH[idx] = (short)hb;
  GpkL[idx] = (short)bf16h(v - bf16f(hb));
}

// dX[slot][p][i]
__global__ void kDX(const float* __restrict__ cb, const float* __restrict__ cc2,
                    const float* __restrict__ cd3, float* __restrict__ dX) {
  int idx = blockIdx.x*256 + threadIdx.x;       // 34*16384 = 557056
  int slot = idx >> 14;
  int rem = idx & 16383;
  int p = rem >> 1, i = rem & 1;
  float v;
  if (slot == 0) {
    v = cb[p*22 + i];
  } else {
    int s1 = slot - 1;
    int k = s1 / 3, j = s1 - 3*k;
    float frac = (float)(j+1) * (1.0f/3.0f);
    if (j == 2) frac = 1.0f;
    int base = p*22 + k*2 + i;
    v = cb[base] + (cc2[base] + cd3[base]*frac)*frac;
  }
  dX[idx] = v;
}

__global__ void kInit(const float* __restrict__ ca, const float* __restrict__ Wh,
                      const float* __restrict__ bh, const float* __restrict__ Wz,
                      const float* __restrict__ bz, float* __restrict__ h,
                      float* __restrict__ z) {
  int idx = blockIdx.x*256 + threadIdx.x;       // 262144
  int c = idx & 31, p = idx >> 5;
  float x0 = ca[p*22 + 0], x1 = ca[p*22 + 1];
  h[idx] = fmaf(x0, Wh[c], fmaf(x1, Wh[32+c], bh[c]));
  z[idx] = fmaf(x0, Wz[c], fmaf(x1, Wz[32+c], bz[c]));
}

// initial xrel = relu(z@gWin+gbin), f32 + packed B-fragment form
__global__ void kXrel0(const float* __restrict__ z, const float* __restrict__ gWin,
                       const float* __restrict__ gbin, float* __restrict__ xrel,
                       short* __restrict__ xpkH, short* __restrict__ xpkL) {
  __shared__ float zl[8][32];
  int t = threadIdx.x, pl = t >> 5, o = t & 31;
  int p = blockIdx.x*8 + pl;
  zl[pl][o] = z[p*32 + o];
  __syncthreads();
  float s = gbin[o];
  #pragma unroll
  for (int i = 0; i < 32; ++i) s = fmaf(zl[pl][i], gWin[i*32 + o], s);
  float xr = fmaxf(s, 0.f);
  xrel[p*32 + o] = xr;
  int b = p >> 9, m = p & 511;
  int c = m >> 5, rr = m & 31;
  int lane = (rr>>3)*16 + (o&15);
  int tt = o >> 4;
  size_t off = (((size_t)(b*16 + c)*2 + tt)*64 + lane)*8 + (rr&7);
  unsigned short hb = bf16h(xr);
  xpkH[off] = (short)hb;
  xpkL[off] = (short)bf16h(xr - bf16f(hb));
}

// ---------------- fused per-stage kernel ----------------
// block = (b, ntile of 16 nodes), XCD-swizzled. 512 thr, 16 points.
__global__ __launch_bounds__(512, 4) void kBF(
    const float* __restrict__ awT, const float* __restrict__ ab,
    const float* __restrict__ dX, float* __restrict__ h, float* __restrict__ z,
    float* __restrict__ kh, float* __restrict__ kz,
    float* __restrict__ xrel,
    const short* __restrict__ ApkH, const short* __restrict__ ApkL,
    const short* __restrict__ xpkH, const short* __restrict__ xpkL,
    short* __restrict__ xpkHo, short* __restrict__ xpkLo,
    const short* __restrict__ GpkH, const short* __restrict__ GpkL,
    const float* __restrict__ fWin, const float* __restrict__ fbin,
    const float* __restrict__ fWmid, const float* __restrict__ fbmid,
    const float* __restrict__ fWout, const float* __restrict__ fbout,
    const float* __restrict__ gWin, const float* __restrict__ gbin,
    const float* __restrict__ gbout, int stage, int slot)
{
  __shared__ float wIn[1024], wMid[1024], wOut[2048], wG[1024];
  __shared__ float bIn[32], bMid[32], bOut[64], bG[32], bGout[1024];
  __shared__ float XR[16][32], AG[16][32], HS[16][32], PL[16][32];
  __shared__ float X1[16][32], X2[16][32], DH[16][32], DZ[16][32];
  __shared__ float scrA[8][16][32];

  int t = threadIdx.x;
  int pl = t >> 5, o = t & 31;
  int w = t >> 6, l = t & 63;
  int bid = blockIdx.x;
  int xcd = bid & 7, sub = (bid>>3)&3, b = bid >> 5;
  int ntile = xcd*4 + sub;
  int n = ntile*16 + pl;
  int pg = b*512 + n;

  // ---- phase 0: stage weights + state loads (LDS writes only) ----
  for (int j = t; j < 1024; j += 512) wIn[j] = fWin[j];
  for (int j = t; j < 1024; j += 512) wMid[j] = fWmid[j];
  for (int j = t; j < 2048; j += 512) wOut[j] = fWout[j];
  for (int j = t; j < 1024; j += 512) wG[j] = gWin[j];
  for (int j = t; j < 1024; j += 512) bGout[j] = gbout[j];
  if (t < 32) bIn[t] = fbin[t];
  else if (t >= 64 && t < 96) bMid[t-64] = fbmid[t-64];
  else if (t >= 128 && t < 192) bOut[t-128] = fbout[t-128];
  else if (t >= 256 && t < 288) bG[t-256] = gbin[t-256];

  XR[pl][o] = xrel[pg*32 + o];
  {
    float hv = h[pg*32 + o];
    float hsv;
    if (stage == 1)      hsv = hv;
    else if (stage == 2) hsv = fmaf(kh[pg*32+o], (1.f/3.f), hv);
    else if (stage == 3) hsv = hv - (1.f/3.f)*kh[pg*32+o] + kh[NPS + pg*32+o];
    else                 hsv = hv + kh[pg*32+o] - kh[NPS + pg*32+o] + kh[2*NPS + pg*32+o];
    HS[pl][o] = hsv;
  }

  // ---- phase A: agg = A[16 rows] @ xrel[b]  (MFMA, split-bf16, global frags) ----
  {
    f32x4 acc0 = {0.f,0.f,0.f,0.f}, acc1 = {0.f,0.f,0.f,0.f};
    #pragma unroll
    for (int cc = 0; cc < 2; ++cc) {
      int c = w*2 + cc;
      size_t aoff = ((size_t)(ntile*16 + c)*64 + l)*8;
      bf16x8 aH = *(const bf16x8*)(ApkH + aoff);
      bf16x8 aL = *(const bf16x8*)(ApkL + aoff);
      size_t boff0 = (((size_t)(b*16 + c)*2 + 0)*64 + l)*8;
      size_t boff1 = (((size_t)(b*16 + c)*2 + 1)*64 + l)*8;
      bf16x8 bH0 = *(const bf16x8*)(xpkH + boff0);
      bf16x8 bL0 = *(const bf16x8*)(xpkL + boff0);
      bf16x8 bH1 = *(const bf16x8*)(xpkH + boff1);
      bf16x8 bL1 = *(const bf16x8*)(xpkL + boff1);
      acc0 = __builtin_amdgcn_mfma_f32_16x16x32_bf16(aL, bH0, acc0, 0, 0, 0);
      acc0 = __builtin_amdgcn_mfma_f32_16x16x32_bf16(aH, bL0, acc0, 0, 0, 0);
      acc0 = __builtin_amdgcn_mfma_f32_16x16x32_bf16(aH, bH0, acc0, 0, 0, 0);
      acc1 = __builtin_amdgcn_mfma_f32_16x16x32_bf16(aL, bH1, acc1, 0, 0, 0);
      acc1 = __builtin_amdgcn_mfma_f32_16x16x32_bf16(aH, bL1, acc1, 0, 0, 0);
      acc1 = __builtin_amdgcn_mfma_f32_16x16x32_bf16(aH, bH1, acc1, 0, 0, 0);
    }
    int lg = l >> 4, ll = l & 15;
    #pragma unroll
    for (int r = 0; r < 4; ++r) {
      scrA[w][lg*4+r][ll]      = acc0[r];
      scrA[w][lg*4+r][16 + ll] = acc1[r];
    }
  }
  __syncthreads();

  // ---- phase B: reduce agg partials; X1 = relu(HS@fWin+fbin) ----
  {
    float s = 0.f;
    #pragma unroll
    for (int ww = 0; ww < 8; ++ww) s += scrA[ww][pl][o];
    AG[pl][o] = s;
  }
  {
    float s = bIn[o];
    #pragma unroll
    for (int i = 0; i < 32; ++i) s = fmaf(HS[pl][i], wIn[i*32 + o], s);
    X1[pl][o] = fmaxf(s, 0.f);
  }
  __syncthreads();

  // ---- phase C: X2; PL = pooled einsum ----
  {
    float s = bMid[o];
    #pragma unroll
    for (int i = 0; i < 32; ++i) s = fmaf(X1[pl][i], wMid[i*32 + o], s);
    X2[pl][o] = fmaxf(s, 0.f);
  }
  {
    const float4* aT = (const float4*)(awT + ((size_t)n*32 + o)*64);
    float s = ab[n*32 + o];
    #pragma unroll
    for (int jj = 0; jj < 8; ++jj) {
      float4 w4 = aT[jj];
      s = fmaf(XR[pl][jj*4+0], w4.x, s);
      s = fmaf(XR[pl][jj*4+1], w4.y, s);
      s = fmaf(XR[pl][jj*4+2], w4.z, s);
      s = fmaf(XR[pl][jj*4+3], w4.w, s);
    }
    #pragma unroll
    for (int jj = 0; jj < 8; ++jj) {
      float4 w4 = aT[8+jj];
      s = fmaf(AG[pl][jj*4+0], w4.x, s);
      s = fmaf(AG[pl][jj*4+1], w4.y, s);
      s = fmaf(AG[pl][jj*4+2], w4.z, s);
      s = fmaf(AG[pl][jj*4+3], w4.w, s);
    }
    PL[pl][o] = s;
  }
  __syncthreads();

  // ---- phase D: vf, dh, RK-h ----
  {
    float s0 = bOut[2*o], s1 = bOut[2*o + 1];
    #pragma unroll
    for (int i = 0; i < 32; ++i) {
      float xv = X2[pl][i];
      s0 = fmaf(xv, wOut[i*64 + 2*o], s0);
      s1 = fmaf(xv, wOut[i*64 + 2*o + 1], s1);
    }
    float vf0 = tanh_fast(s0), vf1 = tanh_fast(s1);
    float dx0 = dX[slot*16384 + pg*2], dx1 = dX[slot*16384 + pg*2 + 1];
    float dhv = fmaf(vf0, dx0, vf1*dx1);
    DH[pl][o] = dhv;
    if (stage < 4) {
      kh[(stage-1)*NPS + pg*32 + o] = dhv;
    } else {
      float hv = h[pg*32+o];
      float k1 = kh[pg*32+o], k2 = kh[NPS+pg*32+o], k3 = kh[2*NPS+pg*32+o];
      h[pg*32+o] = hv + 0.125f*(k1 + 3.f*(k2 + k3) + dhv);
    }
  }
  __syncthreads();

  // ---- phase E: y = PL@gWout (MFMA split-bf16), tanh, dz ----
  {
    int lg = l >> 4, ll = l & 15;
    float4 pA4 = *(const float4*)&PL[ll][lg*8];
    float4 pB4 = *(const float4*)&PL[ll][lg*8 + 4];
    float pv[8] = {pA4.x, pA4.y, pA4.z, pA4.w, pB4.x, pB4.y, pB4.z, pB4.w};
    bf16x8 paH, paL;
    #pragma unroll
    for (int j = 0; j < 8; ++j) {
      unsigned short hb = bf16h(pv[j]);
      paH[j] = (short)hb;
      paL[j] = (short)bf16h(pv[j] - bf16f(hb));
    }
    float p[4][4] = {{0.f,0.f,0.f,0.f},{0.f,0.f,0.f,0.f},{0.f,0.f,0.f,0.f},{0.f,0.f,0.f,0.f}};
    #pragma unroll
    for (int u = 0; u < 8; ++u) {
      int tile = w*8 + u;
      size_t goff = ((size_t)tile*64 + l)*8;
      bf16x8 gH = *(const bf16x8*)(GpkH + goff);
      bf16x8 gL = *(const bf16x8*)(GpkL + goff);
      f32x4 acc = {0.f,0.f,0.f,0.f};
      acc = __builtin_amdgcn_mfma_f32_16x16x32_bf16(paL, gH, acc, 0, 0, 0);
      acc = __builtin_amdgcn_mfma_f32_16x16x32_bf16(paH, gL, acc, 0, 0, 0);
      acc = __builtin_amdgcn_mfma_f32_16x16x32_bf16(paH, gH, acc, 0, 0, 0);
      int col = tile*16 + ll;
      int oo = col & 31;
      int h2 = u >> 1;
      float gb = bGout[col];
      #pragma unroll
      for (int r = 0; r < 4; ++r) {
        float tv = tanh_fast(acc[r] + gb);
        p[r][h2] = fmaf(tv, DH[lg*4 + r][oo], p[r][h2]);
      }
    }
    #pragma unroll
    for (int r = 0; r < 4; ++r) {
      #pragma unroll
      for (int h2 = 0; h2 < 4; ++h2) {
        float v = p[r][h2];
        v += __shfl_xor(v, 1);
        v += __shfl_xor(v, 2);
        v += __shfl_xor(v, 4);
        v += __shfl_xor(v, 8);
        if (ll == r*4 + h2) DZ[lg*4 + r][w*4 + h2] = v;
      }
    }
  }
  __syncthreads();

  // ---- phase F: RK-z, next z, next xrel (f32 + packed) ----
  {
    float dzv = DZ[pl][o];
    float zv = z[pg*32 + o];
    float znv;
    if (stage == 1) {
      kz[pg*32+o] = dzv;
      znv = fmaf(dzv, (1.f/3.f), zv);
    } else if (stage == 2) {
      kz[NPS + pg*32+o] = dzv;
      znv = zv - (1.f/3.f)*kz[pg*32+o] + dzv;
    } else if (stage == 3) {
      kz[2*NPS + pg*32+o] = dzv;
      znv = zv + kz[pg*32+o] - kz[NPS+pg*32+o] + dzv;
    } else {
      float k1 = kz[pg*32+o], k2 = kz[NPS+pg*32+o], k3 = kz[2*NPS+pg*32+o];
      znv = zv + 0.125f*(k1 + 3.f*(k2 + k3) + dzv);
      z[pg*32+o] = znv;
    }
    X1[pl][o] = znv;   // reuse X1 as z_next
  }
  __syncthreads();
  {
    float s = bG[o];
    #pragma unroll
    for (int i = 0; i < 32; ++i) s = fmaf(X1[pl][i], wG[i*32 + o], s);
    float xr = fmaxf(s, 0.f);
    xrel[pg*32 + o] = xr;
    int m = n;
    int c = m >> 5, rr = m & 31;
    int lane = (rr>>3)*16 + (o&15);
    int tt = o >> 4;
    size_t off = (((size_t)(b*16 + c)*2 + tt)*64 + lane)*8 + (rr&7);
    unsigned short hb = bf16h(xr);
    xpkHo[off] = (short)hb;
    xpkLo[off] = (short)bf16h(xr - bf16f(hb));
  }
}

// out[b,0,n,o] = sum_h z[b,n,h]*convW[o,h] + convb[o]
__global__ void kOut(const float* __restrict__ z, const float* __restrict__ convW,
                     const float* __restrict__ convb, float* __restrict__ out) {
  int idx = blockIdx.x*256 + threadIdx.x;   // 98304
  int o = idx % 12, p = idx / 12;
  float s = convb[o];
  #pragma unroll
  for (int hh = 0; hh < 32; ++hh) s = fmaf(z[p*32 + hh], convW[o*32 + hh], s);
  out[idx] = s;
}

extern "C" void kernel_launch(void* const* d_in, const int* in_sizes, int n_in,
                              void* d_out, int out_size, void* d_ws, size_t ws_size,
                              hipStream_t stream) {
  (void)in_sizes; (void)n_in; (void)out_size; (void)ws_size;
  const float* ca     = (const float*)d_in[1];
  const float* cb     = (const float*)d_in[2];
  const float* cc2    = (const float*)d_in[3];
  const float* cd3    = (const float*)d_in[4];
  const float* Wh     = (const float*)d_in[5];
  const float* bh     = (const float*)d_in[6];
  const float* Wz     = (const float*)d_in[7];
  const float* bz     = (const float*)d_in[8];
  const float* fWin   = (const float*)d_in[9];
  const float* fbin   = (const float*)d_in[10];
  const float* fWmid  = (const float*)d_in[11];
  const float* fbmid  = (const float*)d_in[12];
  const float* fWout  = (const float*)d_in[13];
  const float* fbout  = (const float*)d_in[14];
  const float* gWin   = (const float*)d_in[15];
  const float* gbin   = (const float*)d_in[16];
  const float* gE     = (const float*)d_in[17];
  const float* gWpool = (const float*)d_in[18];
  const float* gbpool = (const float*)d_in[19];
  const float* gWout  = (const float*)d_in[20];
  const float* gbout  = (const float*)d_in[21];
  const float* convW  = (const float*)d_in[22];
  const float* convb  = (const float*)d_in[23];
  float* out = (float*)d_out;

  float* wsf  = (float*)d_ws;
  float* awT  = wsf;                   // 1048576
  float* wAb  = awT + 1048576;         // 16384
  float* wDX  = wAb + 16384;           // 557056
  float* wH   = wDX + 557056;          // 262144
  float* wZ   = wH + 262144;           // 262144
  float* wKh  = wZ + 262144;           // 786432
  float* wKz  = wKh + 786432;          // 786432
  float* wXr  = wKz + 786432;          // 262144
  short* ApkH = (short*)(wXr + 262144);   // 262144 shorts
  short* ApkL = ApkH + 262144;
  short* xp0H = ApkL + 262144;            // 262144 shorts each
  short* xp0L = xp0H + 262144;
  short* xp1H = xp0L + 262144;
  short* xp1L = xp1H + 262144;
  short* GpkH = xp1L + 262144;            // 32768 shorts
  short* GpkL = GpkH + 32768;

  kA_softmax<<<512, 256, 0, stream>>>(gE, ApkH, ApkL);
  kAwT<<<512, 256, 0, stream>>>(gE, gWpool, gbpool, awT, wAb);
  kPackGW<<<128, 256, 0, stream>>>(gWout, GpkH, GpkL);
  kDX<<<2176, 256, 0, stream>>>(cb, cc2, cd3, wDX);
  kInit<<<1024, 256, 0, stream>>>(ca, Wh, bh, Wz, bz, wH, wZ);
  kXrel0<<<1024, 256, 0, stream>>>(wZ, gWin, gbin, wXr, xp0H, xp0L);

  for (int ss = 0; ss < 44; ++ss) {
    int stage = (ss & 3) + 1;
    int step = ss >> 2;
    int slot = (ss == 0) ? 0 : (3*step + (ss & 3));
    const short* xiH = (ss & 1) ? xp1H : xp0H;
    const short* xiL = (ss & 1) ? xp1L : xp0L;
    short* xoH = (ss & 1) ? xp0H : xp1H;
    short* xoL = (ss & 1) ? xp0L : xp1L;
    kBF<<<512, 512, 0, stream>>>(awT, wAb, wDX, wH, wZ, wKh, wKz, wXr,
                                 ApkH, ApkL, xiH, xiL, xoH, xoL, GpkH, GpkL,
                                 fWin, fbin, fWmid, fbmid, fWout, fbout,
                                 gWin, gbin, gbout, stage, slot);
  }
  kOut<<<384, 256, 0, stream>>>(wZ, convW, convb, out);
}

// Round 3
// 721.028 us; speedup vs baseline: 1.9754x; 1.4339x over previous
//
#include <hip/hip_runtime.h>
#include <math.h>

#define NPTS 8192
#define NPS  (NPTS*32)

typedef __attribute__((ext_vector_type(8))) short bf16x8;
typedef __attribute__((ext_vector_type(4))) float f32x4;

__device__ __forceinline__ float tanh_fast(float x) {
  float e = __expf(2.0f*x);
  return 1.0f - 2.0f*__builtin_amdgcn_rcpf(e + 1.0f);
}
// Pade [5/4] tanh, max abs err ~1.1e-3, 1 transcendental
__device__ __forceinline__ float tanh_pade(float x) {
  float x2 = x*x;
  float num = x * fmaf(x2, fmaf(x2, 1.0f, 105.0f), 945.0f);
  float den = fmaf(x2, fmaf(x2, 15.0f, 420.0f), 945.0f);
  float r = num * __builtin_amdgcn_rcpf(den);
  return fminf(fmaxf(r, -1.0f), 1.0f);
}
__device__ __forceinline__ unsigned short bf16h(float x) {
  unsigned u = __float_as_uint(x);
  return (unsigned short)((u + 0x7FFFu + ((u>>16)&1u)) >> 16);
}
__device__ __forceinline__ float bf16f(unsigned short h) {
  return __uint_as_float(((unsigned)h)<<16);
}
// pack 8 consecutive f32 (8B-aligned) into hi/lo bf16 fragments
__device__ __forceinline__ void pack_pair(const float* base, bf16x8& H, bf16x8& L) {
  #pragma unroll
  for (int jj = 0; jj < 4; ++jj) {
    float2 q = *(const float2*)(base + 2*jj);
    unsigned short h0 = bf16h(q.x), h1 = bf16h(q.y);
    H[2*jj]   = (short)h0; H[2*jj+1] = (short)h1;
    L[2*jj]   = (short)bf16h(q.x - bf16f(h0));
    L[2*jj+1] = (short)bf16h(q.y - bf16f(h1));
  }
}

// ---------------- prologue kernels ----------------

// A = softmax(relu(gE@gE^T)) row n; write packed bf16 hi/lo A-fragments.
__global__ void kA_softmax(const float* __restrict__ gE, short* __restrict__ ApkH,
                           short* __restrict__ ApkL) {
  __shared__ float gn[16];
  __shared__ float red[256];
  int n = blockIdx.x, t = threadIdx.x;
  if (t < 16) gn[t] = gE[n*16 + t];
  __syncthreads();
  float e0, e1;
  {
    float d = 0.f;
    #pragma unroll
    for (int dd = 0; dd < 16; ++dd) d = fmaf(gn[dd], gE[t*16 + dd], d);
    e0 = __expf(fmaxf(d, 0.f));
  }
  {
    float d = 0.f;
    #pragma unroll
    for (int dd = 0; dd < 16; ++dd) d = fmaf(gn[dd], gE[(t+256)*16 + dd], d);
    e1 = __expf(fmaxf(d, 0.f));
  }
  red[t] = e0 + e1;
  __syncthreads();
  for (int off = 128; off > 0; off >>= 1) {
    if (t < off) red[t] += red[t+off];
    __syncthreads();
  }
  float inv = __builtin_amdgcn_rcpf(red[0]);
  int nt = n >> 4;
  #pragma unroll
  for (int half = 0; half < 2; ++half) {
    int k = t + half*256;
    float v = (half ? e1 : e0) * inv;
    int c = k >> 5, g = (k>>3)&3, j = k&7;
    int l = g*16 + (n&15);
    size_t off2 = ((size_t)(nt*16 + c)*64 + l)*8 + j;
    unsigned short hb = bf16h(v);
    ApkH[off2] = (short)hb;
    ApkL[off2] = (short)bf16h(v - bf16f(hb));
  }
}

// awT[n][ii][o] = sum_d gE[n][d]*gWpool[d][ii][o]  (native gWpool col order, coalesced)
__global__ __launch_bounds__(256) void kAwT2(const float* __restrict__ gE,
                      const float* __restrict__ gWpool,
                      const float* __restrict__ gbpool,
                      float* __restrict__ awT, float* __restrict__ ab) {
  __shared__ float gn[2][16];
  int t = threadIdx.x; int n0 = blockIdx.x*2;
  if (t < 32) gn[t>>4][t&15] = gE[n0*16 + t];
  __syncthreads();
  #pragma unroll
  for (int rep = 0; rep < 2; ++rep) {
    int c4 = t + rep*256;
    float4 a0 = {0,0,0,0}, a1 = {0,0,0,0};
    #pragma unroll
    for (int d = 0; d < 16; ++d) {
      float4 wv = *(const float4*)&gWpool[d*2048 + c4*4];
      float g0 = gn[0][d], g1 = gn[1][d];
      a0.x = fmaf(g0, wv.x, a0.x); a0.y = fmaf(g0, wv.y, a0.y);
      a0.z = fmaf(g0, wv.z, a0.z); a0.w = fmaf(g0, wv.w, a0.w);
      a1.x = fmaf(g1, wv.x, a1.x); a1.y = fmaf(g1, wv.y, a1.y);
      a1.z = fmaf(g1, wv.z, a1.z); a1.w = fmaf(g1, wv.w, a1.w);
    }
    *(float4*)&awT[(size_t)n0*2048 + c4*4]     = a0;
    *(float4*)&awT[(size_t)(n0+1)*2048 + c4*4] = a1;
  }
  if (t < 64) {
    int nn = n0 + (t>>5), o = t&31;
    float s = 0.f;
    #pragma unroll
    for (int d = 0; d < 16; ++d) s = fmaf(gn[t>>5][d], gbpool[d*32 + o], s);
    ab[nn*32 + o] = s;
  }
}

// gWout (32x1024) -> packed bf16 hi/lo B-fragments
__global__ void kPackGW(const float* __restrict__ gWout, short* __restrict__ GpkH,
                        short* __restrict__ GpkL) {
  int idx = blockIdx.x*256 + threadIdx.x;   // 32768
  int j = idx & 7, l = (idx>>3)&63, tl = idx>>9;
  int col = tl*16 + (l&15);
  int k = ((l>>4)&3)*8 + j;
  float v = gWout[k*1024 + col];
  unsigned short hb = bf16h(v);
  GpkH[idx] = (short)hb;
  GpkL[idx] = (short)bf16h(v - bf16f(hb));
}

// pack fWin(2 tiles), fWmid(2), fWout(4), gWin(2) -> 10 tiles of B-fragments
__global__ void kPackW(const float* __restrict__ fWin, const float* __restrict__ fWmid,
                       const float* __restrict__ fWout, const float* __restrict__ gWin,
                       short* __restrict__ WpkH, short* __restrict__ WpkL) {
  int idx = blockIdx.x*256 + threadIdx.x;   // 5120
  if (idx >= 5120) return;
  int j = idx & 7, l = (idx>>3)&63, T = idx>>9;
  int k = ((l>>4)&3)*8 + j;
  const float* M; int cols, tl;
  if (T < 2)      { M = fWin;  cols = 32; tl = T;   }
  else if (T < 4) { M = fWmid; cols = 32; tl = T-2; }
  else if (T < 8) { M = fWout; cols = 64; tl = T-4; }
  else            { M = gWin;  cols = 32; tl = T-8; }
  float v = M[k*cols + tl*16 + (l&15)];
  unsigned short hb = bf16h(v);
  WpkH[idx] = (short)hb;
  WpkL[idx] = (short)bf16h(v - bf16f(hb));
}

// dX[slot][p][i]
__global__ void kDX(const float* __restrict__ cb, const float* __restrict__ cc2,
                    const float* __restrict__ cd3, float* __restrict__ dX) {
  int idx = blockIdx.x*256 + threadIdx.x;       // 34*16384 = 557056
  int slot = idx >> 14;
  int rem = idx & 16383;
  int p = rem >> 1, i = rem & 1;
  float v;
  if (slot == 0) {
    v = cb[p*22 + i];
  } else {
    int s1 = slot - 1;
    int k = s1 / 3, j = s1 - 3*k;
    float frac = (float)(j+1) * (1.0f/3.0f);
    if (j == 2) frac = 1.0f;
    int base = p*22 + k*2 + i;
    v = cb[base] + (cc2[base] + cd3[base]*frac)*frac;
  }
  dX[idx] = v;
}

__global__ void kInit(const float* __restrict__ ca, const float* __restrict__ Wh,
                      const float* __restrict__ bh, const float* __restrict__ Wz,
                      const float* __restrict__ bz, float* __restrict__ h,
                      float* __restrict__ z) {
  int idx = blockIdx.x*256 + threadIdx.x;       // 262144
  int c = idx & 31, p = idx >> 5;
  float x0 = ca[p*22 + 0], x1 = ca[p*22 + 1];
  h[idx] = fmaf(x0, Wh[c], fmaf(x1, Wh[32+c], bh[c]));
  z[idx] = fmaf(x0, Wz[c], fmaf(x1, Wz[32+c], bz[c]));
}

// initial xrel = relu(z@gWin+gbin), f32 + packed B-fragment form
__global__ void kXrel0(const float* __restrict__ z, const float* __restrict__ gWin,
                       const float* __restrict__ gbin, float* __restrict__ xrel,
                       short* __restrict__ xpkH, short* __restrict__ xpkL) {
  __shared__ float zl[8][32];
  int t = threadIdx.x, pl = t >> 5, o = t & 31;
  int p = blockIdx.x*8 + pl;
  zl[pl][o] = z[p*32 + o];
  __syncthreads();
  float s = gbin[o];
  #pragma unroll
  for (int i = 0; i < 32; ++i) s = fmaf(zl[pl][i], gWin[i*32 + o], s);
  float xr = fmaxf(s, 0.f);
  xrel[p*32 + o] = xr;
  int b = p >> 9, m = p & 511;
  int c = m >> 5, rr = m & 31;
  int lane = (rr>>3)*16 + (o&15);
  int tt = o >> 4;
  size_t off = (((size_t)(b*16 + c)*2 + tt)*64 + lane)*8 + (rr&7);
  unsigned short hb = bf16h(xr);
  xpkH[off] = (short)hb;
  xpkL[off] = (short)bf16h(xr - bf16f(hb));
}

// ---------------- fused per-stage kernel ----------------
// 512 thr = 8 waves, 16 points, grid 512 (b x ntile, XCD-swizzled).
// Wave roles: w0/w1 MFMA chain, w2/w3 AG-reduce, w4-7 pool; all: phases A,E,F.
__global__ __launch_bounds__(512, 4) void kBF(
    const float* __restrict__ awT, const float* __restrict__ ab,
    const float* __restrict__ dX, float* __restrict__ h, float* __restrict__ z,
    float* __restrict__ kh, float* __restrict__ kz,
    float* __restrict__ xrel,
    const short* __restrict__ ApkH, const short* __restrict__ ApkL,
    const short* __restrict__ xpkH, const short* __restrict__ xpkL,
    short* __restrict__ xpkHo, short* __restrict__ xpkLo,
    const short* __restrict__ GpkH, const short* __restrict__ GpkL,
    const short* __restrict__ WpkH, const short* __restrict__ WpkL,
    const float* __restrict__ fbin, const float* __restrict__ fbmid,
    const float* __restrict__ fbout, const float* __restrict__ gbin,
    const float* __restrict__ gbout, int stage, int slot)
{
  __shared__ float scrA[8][16][32];
  __shared__ float bGl[1024];
  __shared__ float HS[16*34], X1[16*34], X2[16*34], PLb[16*34];
  __shared__ float XR[16*36], AG[16*36];
  __shared__ float DHT[32*20];
  __shared__ float DZ[16*33];

  int t = threadIdx.x;
  int pl = t >> 5, o = t & 31;
  int w = t >> 6, l = t & 63;
  int ll = l & 15, lg = l >> 4;
  int bid = blockIdx.x;
  int xcd = bid & 7, sub = (bid >> 3) & 3, b = bid >> 5;
  int ntile = xcd*4 + sub;
  int pgbase = b*512 + ntile*16;
  int pg = pgbase + pl;

  // ---- phase 0: stage bGout, XR, HS ----
  bGl[t] = gbout[t]; bGl[t+512] = gbout[t+512];
  XR[pl*36 + o] = xrel[pg*32 + o];
  {
    float hv = h[pg*32 + o]; float hsv;
    if (stage == 1)      hsv = hv;
    else if (stage == 2) hsv = fmaf(kh[pg*32+o], (1.f/3.f), hv);
    else if (stage == 3) hsv = hv - (1.f/3.f)*kh[pg*32+o] + kh[NPS + pg*32+o];
    else                 hsv = hv + kh[pg*32+o] - kh[NPS + pg*32+o] + kh[2*NPS + pg*32+o];
    HS[pl*34 + o] = hsv;
  }

  // ---- phase A: agg MFMA (split-bf16, global frags) ----
  {
    f32x4 acc0 = {0.f,0.f,0.f,0.f}, acc1 = {0.f,0.f,0.f,0.f};
    #pragma unroll
    for (int cc = 0; cc < 2; ++cc) {
      int c = w*2 + cc;
      size_t aoff = ((size_t)(ntile*16 + c)*64 + l)*8;
      bf16x8 aH = *(const bf16x8*)(ApkH + aoff);
      bf16x8 aL = *(const bf16x8*)(ApkL + aoff);
      size_t boff0 = (((size_t)(b*16 + c)*2 + 0)*64 + l)*8;
      size_t boff1 = (((size_t)(b*16 + c)*2 + 1)*64 + l)*8;
      bf16x8 bH0 = *(const bf16x8*)(xpkH + boff0);
      bf16x8 bL0 = *(const bf16x8*)(xpkL + boff0);
      bf16x8 bH1 = *(const bf16x8*)(xpkH + boff1);
      bf16x8 bL1 = *(const bf16x8*)(xpkL + boff1);
      acc0 = __builtin_amdgcn_mfma_f32_16x16x32_bf16(aL, bH0, acc0, 0, 0, 0);
      acc0 = __builtin_amdgcn_mfma_f32_16x16x32_bf16(aH, bL0, acc0, 0, 0, 0);
      acc0 = __builtin_amdgcn_mfma_f32_16x16x32_bf16(aH, bH0, acc0, 0, 0, 0);
      acc1 = __builtin_amdgcn_mfma_f32_16x16x32_bf16(aL, bH1, acc1, 0, 0, 0);
      acc1 = __builtin_amdgcn_mfma_f32_16x16x32_bf16(aH, bL1, acc1, 0, 0, 0);
      acc1 = __builtin_amdgcn_mfma_f32_16x16x32_bf16(aH, bH1, acc1, 0, 0, 0);
    }
    #pragma unroll
    for (int r = 0; r < 4; ++r) {
      scrA[w][lg*4+r][ll]      = acc0[r];
      scrA[w][lg*4+r][16 + ll] = acc1[r];
    }
  }
  __syncthreads();   // bar1

  // ---- B1: chain L1 | AG reduce | pool part 1 ----
  float plp0 = 0.f, plp1 = 0.f;
  if (w < 2) {
    bf16x8 aH, aL; pack_pair(&HS[ll*34 + lg*8], aH, aL);
    bf16x8 bH = *(const bf16x8*)(WpkH + (size_t)w*512 + l*8);
    bf16x8 bL = *(const bf16x8*)(WpkL + (size_t)w*512 + l*8);
    f32x4 acc = {0.f,0.f,0.f,0.f};
    acc = __builtin_amdgcn_mfma_f32_16x16x32_bf16(aL, bH, acc, 0, 0, 0);
    acc = __builtin_amdgcn_mfma_f32_16x16x32_bf16(aH, bL, acc, 0, 0, 0);
    acc = __builtin_amdgcn_mfma_f32_16x16x32_bf16(aH, bH, acc, 0, 0, 0);
    int col = w*16 + ll;
    float bb = fbin[col];
    #pragma unroll
    for (int r = 0; r < 4; ++r) X1[(lg*4+r)*34 + col] = fmaxf(acc[r] + bb, 0.f);
  } else if (w < 4) {
    int base = (t - 128)*4;
    #pragma unroll
    for (int jj = 0; jj < 4; ++jj) {
      int s = base + jj; int sp = s>>5, so = s&31;
      float v = 0.f;
      #pragma unroll
      for (int ww = 0; ww < 8; ++ww) v += scrA[ww][sp][so];
      AG[sp*36 + so] = v;
    }
  } else {
    #pragma unroll
    for (int half = 0; half < 2; ++half) {
      int s = (t - 256) + half*256;
      int sp = s>>5, so = s&31;
      int nn = ntile*16 + sp;
      const float* awp = awT + (size_t)nn*2048 + so;
      const float4* xr4 = (const float4*)&XR[sp*36];
      float acc = 0.f;
      #pragma unroll
      for (int q = 0; q < 8; ++q) {
        float4 xv = xr4[q];
        acc = fmaf(xv.x, awp[(q*4+0)*32], acc);
        acc = fmaf(xv.y, awp[(q*4+1)*32], acc);
        acc = fmaf(xv.z, awp[(q*4+2)*32], acc);
        acc = fmaf(xv.w, awp[(q*4+3)*32], acc);
      }
      if (half == 0) plp0 = acc; else plp1 = acc;
    }
  }
  __syncthreads();   // bar2

  // ---- B2: chain L2 | pool part 2 + PL write ----
  if (w < 2) {
    bf16x8 aH, aL; pack_pair(&X1[ll*34 + lg*8], aH, aL);
    bf16x8 bH = *(const bf16x8*)(WpkH + (size_t)(2+w)*512 + l*8);
    bf16x8 bL = *(const bf16x8*)(WpkL + (size_t)(2+w)*512 + l*8);
    f32x4 acc = {0.f,0.f,0.f,0.f};
    acc = __builtin_amdgcn_mfma_f32_16x16x32_bf16(aL, bH, acc, 0, 0, 0);
    acc = __builtin_amdgcn_mfma_f32_16x16x32_bf16(aH, bL, acc, 0, 0, 0);
    acc = __builtin_amdgcn_mfma_f32_16x16x32_bf16(aH, bH, acc, 0, 0, 0);
    int col = w*16 + ll;
    float bb = fbmid[col];
    #pragma unroll
    for (int r = 0; r < 4; ++r) X2[(lg*4+r)*34 + col] = fmaxf(acc[r] + bb, 0.f);
  } else if (w >= 4) {
    #pragma unroll
    for (int half = 0; half < 2; ++half) {
      int s = (t - 256) + half*256;
      int sp = s>>5, so = s&31;
      int nn = ntile*16 + sp;
      const float* awp = awT + (size_t)nn*2048 + 1024 + so;
      const float4* ag4 = (const float4*)&AG[sp*36];
      float acc = (half == 0) ? plp0 : plp1;
      #pragma unroll
      for (int q = 0; q < 8; ++q) {
        float4 av = ag4[q];
        acc = fmaf(av.x, awp[(q*4+0)*32], acc);
        acc = fmaf(av.y, awp[(q*4+1)*32], acc);
        acc = fmaf(av.z, awp[(q*4+2)*32], acc);
        acc = fmaf(av.w, awp[(q*4+3)*32], acc);
      }
      PLb[sp*34 + so] = acc + ab[nn*32 + so];
    }
  }
  __syncthreads();   // bar3

  // ---- D: fWout + tanh + dh -> DHT (waves 0,1) ----
  if (w < 2) {
    bf16x8 aH, aL; pack_pair(&X2[ll*34 + lg*8], aH, aL);
    float vf[2][4];
    #pragma unroll
    for (int e = 0; e < 2; ++e) {
      int T = 2*w + e;
      bf16x8 bH = *(const bf16x8*)(WpkH + (size_t)(4+T)*512 + l*8);
      bf16x8 bL = *(const bf16x8*)(WpkL + (size_t)(4+T)*512 + l*8);
      f32x4 acc = {0.f,0.f,0.f,0.f};
      acc = __builtin_amdgcn_mfma_f32_16x16x32_bf16(aL, bH, acc, 0, 0, 0);
      acc = __builtin_amdgcn_mfma_f32_16x16x32_bf16(aH, bL, acc, 0, 0, 0);
      acc = __builtin_amdgcn_mfma_f32_16x16x32_bf16(aH, bH, acc, 0, 0, 0);
      int col = T*16 + ll;
      float bb = fbout[col];
      #pragma unroll
      for (int r = 0; r < 4; ++r) vf[e][r] = tanh_fast(acc[r] + bb);
    }
    float2 dxv[4];
    #pragma unroll
    for (int r = 0; r < 4; ++r)
      dxv[r] = *(const float2*)&dX[(size_t)slot*16384 + (size_t)(pgbase + lg*4 + r)*2];
    #pragma unroll
    for (int e = 0; e < 2; ++e) {
      int T = 2*w + e;
      float vo[4];
      #pragma unroll
      for (int r = 0; r < 4; ++r) vo[r] = __shfl_xor(vf[e][r], 1);
      if (!(l & 1)) {
        int hh = T*8 + (ll>>1);
        float4 dv;
        dv.x = vf[e][0]*dxv[0].x + vo[0]*dxv[0].y;
        dv.y = vf[e][1]*dxv[1].x + vo[1]*dxv[1].y;
        dv.z = vf[e][2]*dxv[2].x + vo[2]*dxv[2].y;
        dv.w = vf[e][3]*dxv[3].x + vo[3]*dxv[3].y;
        *(float4*)&DHT[hh*20 + lg*4] = dv;
      }
    }
  }
  __syncthreads();   // bar4

  // ---- E: vg = tanh(PL@gWout + gbout), dz partial + shfl reduce ----
  {
    bf16x8 paH, paL; pack_pair(&PLb[ll*34 + lg*8], paH, paL);
    float p[4][4] = {{0.f,0.f,0.f,0.f},{0.f,0.f,0.f,0.f},{0.f,0.f,0.f,0.f},{0.f,0.f,0.f,0.f}};
    #pragma unroll
    for (int u = 0; u < 8; ++u) {
      int tile = w*8 + u;
      size_t goff = ((size_t)tile*64 + l)*8;
      bf16x8 gH = *(const bf16x8*)(GpkH + goff);
      bf16x8 gL = *(const bf16x8*)(GpkL + goff);
      f32x4 acc = {0.f,0.f,0.f,0.f};
      acc = __builtin_amdgcn_mfma_f32_16x16x32_bf16(paL, gH, acc, 0, 0, 0);
      acc = __builtin_amdgcn_mfma_f32_16x16x32_bf16(paH, gL, acc, 0, 0, 0);
      acc = __builtin_amdgcn_mfma_f32_16x16x32_bf16(paH, gH, acc, 0, 0, 0);
      int col = tile*16 + ll, oo = col & 31;
      float gb = bGl[col];
      float4 dh4 = *(const float4*)&DHT[oo*20 + lg*4];
      int h2 = u >> 1;
      float da[4] = {dh4.x, dh4.y, dh4.z, dh4.w};
      #pragma unroll
      for (int r = 0; r < 4; ++r) {
        float tv = tanh_pade(acc[r] + gb);
        p[r][h2] = fmaf(tv, da[r], p[r][h2]);
      }
    }
    #pragma unroll
    for (int r = 0; r < 4; ++r) {
      #pragma unroll
      for (int h2 = 0; h2 < 4; ++h2) {
        float v = p[r][h2];
        v += __shfl_xor(v, 1);
        v += __shfl_xor(v, 2);
        v += __shfl_xor(v, 4);
        v += __shfl_xor(v, 8);
        if (ll == r*4 + h2) DZ[(lg*4 + r)*33 + w*4 + h2] = v;
      }
    }
  }
  __syncthreads();   // bar5

  // ---- F: RK bookkeeping (h & z), z_next -> X1 ----
  {
    float dzv = DZ[pl*33 + o];
    float dhv = DHT[o*20 + pl];
    if (stage < 4) {
      kh[(size_t)(stage-1)*NPS + pg*32 + o] = dhv;
    } else {
      float hv = h[pg*32+o];
      float k1 = kh[pg*32+o], k2 = kh[NPS+pg*32+o], k3 = kh[2*NPS+pg*32+o];
      h[pg*32+o] = hv + 0.125f*(k1 + 3.f*(k2 + k3) + dhv);
    }
    float zv = z[pg*32 + o];
    float znv;
    if (stage == 1) {
      kz[pg*32+o] = dzv;
      znv = fmaf(dzv, (1.f/3.f), zv);
    } else if (stage == 2) {
      kz[NPS + pg*32+o] = dzv;
      znv = zv - (1.f/3.f)*kz[pg*32+o] + dzv;
    } else if (stage == 3) {
      kz[2*NPS + pg*32+o] = dzv;
      znv = zv + kz[pg*32+o] - kz[NPS+pg*32+o] + dzv;
    } else {
      float k1 = kz[pg*32+o], k2 = kz[NPS+pg*32+o], k3 = kz[2*NPS+pg*32+o];
      znv = zv + 0.125f*(k1 + 3.f*(k2 + k3) + dzv);
      z[pg*32+o] = znv;
    }
    X1[pl*34 + o] = znv;   // reuse X1 as z_next
  }
  __syncthreads();   // bar6

  // ---- G: xrel_next = relu(z_next@gWin+gbin) via MFMA; store f32 + packed ----
  if (w < 2) {
    bf16x8 aH, aL; pack_pair(&X1[ll*34 + lg*8], aH, aL);
    bf16x8 bH = *(const bf16x8*)(WpkH + (size_t)(8+w)*512 + l*8);
    bf16x8 bL = *(const bf16x8*)(WpkL + (size_t)(8+w)*512 + l*8);
    f32x4 acc = {0.f,0.f,0.f,0.f};
    acc = __builtin_amdgcn_mfma_f32_16x16x32_bf16(aL, bH, acc, 0, 0, 0);
    acc = __builtin_amdgcn_mfma_f32_16x16x32_bf16(aH, bL, acc, 0, 0, 0);
    acc = __builtin_amdgcn_mfma_f32_16x16x32_bf16(aH, bH, acc, 0, 0, 0);
    int col = w*16 + ll;
    float bb = gbin[col];
    int hp = ntile & 1, cch = ntile >> 1;
    #pragma unroll
    for (int r = 0; r < 4; ++r) {
      float xr = fmaxf(acc[r] + bb, 0.f);
      int row = lg*4 + r;
      xrel[(size_t)(pgbase + row)*32 + col] = xr;
      int rr = hp*16 + row;
      size_t off = (((size_t)(b*16 + cch)*2 + w)*64 + ((rr>>3)*16 + ll))*8 + (rr&7);
      unsigned short hb = bf16h(xr);
      xpkHo[off] = (short)hb;
      xpkLo[off] = (short)bf16h(xr - bf16f(hb));
    }
  }
}

// out[b,0,n,o] = sum_h z[b,n,h]*convW[o,h] + convb[o]
__global__ void kOut(const float* __restrict__ z, const float* __restrict__ convW,
                     const float* __restrict__ convb, float* __restrict__ out) {
  int idx = blockIdx.x*256 + threadIdx.x;   // 98304
  int o = idx % 12, p = idx / 12;
  float s = convb[o];
  #pragma unroll
  for (int hh = 0; hh < 32; ++hh) s = fmaf(z[p*32 + hh], convW[o*32 + hh], s);
  out[idx] = s;
}

extern "C" void kernel_launch(void* const* d_in, const int* in_sizes, int n_in,
                              void* d_out, int out_size, void* d_ws, size_t ws_size,
                              hipStream_t stream) {
  (void)in_sizes; (void)n_in; (void)out_size; (void)ws_size;
  const float* ca     = (const float*)d_in[1];
  const float* cb     = (const float*)d_in[2];
  const float* cc2    = (const float*)d_in[3];
  const float* cd3    = (const float*)d_in[4];
  const float* Wh     = (const float*)d_in[5];
  const float* bh     = (const float*)d_in[6];
  const float* Wz     = (const float*)d_in[7];
  const float* bz     = (const float*)d_in[8];
  const float* fWin   = (const float*)d_in[9];
  const float* fbin   = (const float*)d_in[10];
  const float* fWmid  = (const float*)d_in[11];
  const float* fbmid  = (const float*)d_in[12];
  const float* fWout  = (const float*)d_in[13];
  const float* fbout  = (const float*)d_in[14];
  const float* gWin   = (const float*)d_in[15];
  const float* gbin   = (const float*)d_in[16];
  const float* gE     = (const float*)d_in[17];
  const float* gWpool = (const float*)d_in[18];
  const float* gbpool = (const float*)d_in[19];
  const float* gWout  = (const float*)d_in[20];
  const float* gbout  = (const float*)d_in[21];
  const float* convW  = (const float*)d_in[22];
  const float* convb  = (const float*)d_in[23];
  float* out = (float*)d_out;

  float* wsf  = (float*)d_ws;
  float* awT  = wsf;                   // 1048576
  float* wAb  = awT + 1048576;         // 16384
  float* wDX  = wAb + 16384;           // 557056
  float* wH   = wDX + 557056;          // 262144
  float* wZ   = wH + 262144;           // 262144
  float* wKh  = wZ + 262144;           // 786432
  float* wKz  = wKh + 786432;          // 786432
  float* wXr  = wKz + 786432;          // 262144
  short* ApkH = (short*)(wXr + 262144);   // 262144 shorts each below
  short* ApkL = ApkH + 262144;
  short* xp0H = ApkL + 262144;
  short* xp0L = xp0H + 262144;
  short* xp1H = xp0L + 262144;
  short* xp1L = xp1H + 262144;
  short* GpkH = xp1L + 262144;            // 32768
  short* GpkL = GpkH + 32768;             // 32768
  short* WpkH = GpkL + 32768;             // 5120
  short* WpkL = WpkH + 5120;              // 5120

  kA_softmax<<<512, 256, 0, stream>>>(gE, ApkH, ApkL);
  kAwT2<<<256, 256, 0, stream>>>(gE, gWpool, gbpool, awT, wAb);
  kPackGW<<<128, 256, 0, stream>>>(gWout, GpkH, GpkL);
  kPackW<<<20, 256, 0, stream>>>(fWin, fWmid, fWout, gWin, WpkH, WpkL);
  kDX<<<2176, 256, 0, stream>>>(cb, cc2, cd3, wDX);
  kInit<<<1024, 256, 0, stream>>>(ca, Wh, bh, Wz, bz, wH, wZ);
  kXrel0<<<1024, 256, 0, stream>>>(wZ, gWin, gbin, wXr, xp0H, xp0L);

  for (int ss = 0; ss < 44; ++ss) {
    int stage = (ss & 3) + 1;
    int step = ss >> 2;
    int slot = (ss == 0) ? 0 : (3*step + (ss & 3));
    const short* xiH = (ss & 1) ? xp1H : xp0H;
    const short* xiL = (ss & 1) ? xp1L : xp0L;
    short* xoH = (ss & 1) ? xp0H : xp1H;
    short* xoL = (ss & 1) ? xp0L : xp1L;
    kBF<<<512, 512, 0, stream>>>(awT, wAb, wDX, wH, wZ, wKh, wKz, wXr,
                                 ApkH, ApkL, xiH, xiL, xoH, xoL, GpkH, GpkL,
                                 WpkH, WpkL, fbin, fbmid, fbout, gbin, gbout,
                                 stage, slot);
  }
  kOut<<<384, 256, 0, stream>>>(wZ, convW, convb, out);
}

// Round 4
// 689.582 us; speedup vs baseline: 2.0655x; 1.0456x over previous
//
#include <hip/hip_runtime.h>
#include <math.h>

#define NPTS 8192
#define NPS  (NPTS*32)

typedef __attribute__((ext_vector_type(8))) short bf16x8;
typedef __attribute__((ext_vector_type(4))) float f32x4;

__device__ __forceinline__ float tanh_fast(float x) {
  float e = __expf(2.0f*x);
  return 1.0f - 2.0f*__builtin_amdgcn_rcpf(e + 1.0f);
}
__device__ __forceinline__ unsigned short bf16h(float x) {
  unsigned u = __float_as_uint(x);
  return (unsigned short)((u + 0x7FFFu + ((u>>16)&1u)) >> 16);
}
__device__ __forceinline__ float bf16f(unsigned short h) {
  return __uint_as_float(((unsigned)h)<<16);
}
// pack 8 consecutive f32 (8B-aligned) into a hi bf16 fragment
__device__ __forceinline__ bf16x8 pack_hi(const float* base) {
  bf16x8 H;
  #pragma unroll
  for (int jj = 0; jj < 4; ++jj) {
    float2 q = *(const float2*)(base + 2*jj);
    H[2*jj]   = (short)bf16h(q.x);
    H[2*jj+1] = (short)bf16h(q.y);
  }
  return H;
}

// ---------------- prologue kernels ----------------

// A = softmax(relu(gE@gE^T)) row n; write packed bf16 hi/lo A-fragments.
__global__ void kA_softmax(const float* __restrict__ gE, short* __restrict__ ApkH,
                           short* __restrict__ ApkL) {
  __shared__ float gn[16];
  __shared__ float red[256];
  int n = blockIdx.x, t = threadIdx.x;
  if (t < 16) gn[t] = gE[n*16 + t];
  __syncthreads();
  float e0, e1;
  {
    float d = 0.f;
    #pragma unroll
    for (int dd = 0; dd < 16; ++dd) d = fmaf(gn[dd], gE[t*16 + dd], d);
    e0 = __expf(fmaxf(d, 0.f));
  }
  {
    float d = 0.f;
    #pragma unroll
    for (int dd = 0; dd < 16; ++dd) d = fmaf(gn[dd], gE[(t+256)*16 + dd], d);
    e1 = __expf(fmaxf(d, 0.f));
  }
  red[t] = e0 + e1;
  __syncthreads();
  for (int off = 128; off > 0; off >>= 1) {
    if (t < off) red[t] += red[t+off];
    __syncthreads();
  }
  float inv = __builtin_amdgcn_rcpf(red[0]);
  int nt = n >> 4;
  #pragma unroll
  for (int half = 0; half < 2; ++half) {
    int k = t + half*256;
    float v = (half ? e1 : e0) * inv;
    int c = k >> 5, g = (k>>3)&3, j = k&7;
    int l = g*16 + (n&15);
    size_t off2 = ((size_t)(nt*16 + c)*64 + l)*8 + j;
    unsigned short hb = bf16h(v);
    ApkH[off2] = (short)hb;
    ApkL[off2] = (short)bf16h(v - bf16f(hb));
  }
}

// awb[n][q][o] = packed bf16 pair (ii=2q lo16, ii=2q+1 hi16) of
//   sum_d gE[n][d]*gWpool[d][ii][o];  ab[n][o]
__global__ __launch_bounds__(256) void kAwB(const float* __restrict__ gE,
                      const float* __restrict__ gWpool,
                      const float* __restrict__ gbpool,
                      unsigned* __restrict__ awb, float* __restrict__ ab) {
  __shared__ float gn[16];
  int n = blockIdx.x, t = threadIdx.x;
  if (t < 16) gn[t] = gE[n*16 + t];
  __syncthreads();
  #pragma unroll
  for (int r = 0; r < 4; ++r) {
    int e = t + r*256;
    int q = e >> 5, o = e & 31;
    float s0 = 0.f, s1 = 0.f;
    #pragma unroll
    for (int d = 0; d < 16; ++d) {
      float g = gn[d];
      s0 = fmaf(g, gWpool[d*2048 + (2*q)*32 + o], s0);
      s1 = fmaf(g, gWpool[d*2048 + (2*q+1)*32 + o], s1);
    }
    awb[(size_t)n*1024 + e] = (unsigned)bf16h(s0) | ((unsigned)bf16h(s1) << 16);
  }
  if (t < 32) {
    float s = 0.f;
    #pragma unroll
    for (int d = 0; d < 16; ++d) s = fmaf(gn[d], gbpool[d*32 + t], s);
    ab[n*32 + t] = s;
  }
}

// gWout (32x1024) -> packed bf16 hi/lo B-fragments
__global__ void kPackGW(const float* __restrict__ gWout, short* __restrict__ GpkH,
                        short* __restrict__ GpkL) {
  int idx = blockIdx.x*256 + threadIdx.x;   // 32768
  int j = idx & 7, l = (idx>>3)&63, tl = idx>>9;
  int col = tl*16 + (l&15);
  int k = ((l>>4)&3)*8 + j;
  float v = gWout[k*1024 + col];
  unsigned short hb = bf16h(v);
  GpkH[idx] = (short)hb;
  GpkL[idx] = (short)bf16h(v - bf16f(hb));
}

// pack fWin(2 tiles), fWmid(2), fWout(4), gWin(2) -> 10 tiles of B-fragments
__global__ void kPackW(const float* __restrict__ fWin, const float* __restrict__ fWmid,
                       const float* __restrict__ fWout, const float* __restrict__ gWin,
                       short* __restrict__ WpkH, short* __restrict__ WpkL) {
  int idx = blockIdx.x*256 + threadIdx.x;   // 5120
  if (idx >= 5120) return;
  int j = idx & 7, l = (idx>>3)&63, T = idx>>9;
  int k = ((l>>4)&3)*8 + j;
  const float* M; int cols, tl;
  if (T < 2)      { M = fWin;  cols = 32; tl = T;   }
  else if (T < 4) { M = fWmid; cols = 32; tl = T-2; }
  else if (T < 8) { M = fWout; cols = 64; tl = T-4; }
  else            { M = gWin;  cols = 32; tl = T-8; }
  float v = M[k*cols + tl*16 + (l&15)];
  unsigned short hb = bf16h(v);
  WpkH[idx] = (short)hb;
  WpkL[idx] = (short)bf16h(v - bf16f(hb));
}

// dX[slot][p][i]
__global__ void kDX(const float* __restrict__ cb, const float* __restrict__ cc2,
                    const float* __restrict__ cd3, float* __restrict__ dX) {
  int idx = blockIdx.x*256 + threadIdx.x;       // 34*16384 = 557056
  int slot = idx >> 14;
  int rem = idx & 16383;
  int p = rem >> 1, i = rem & 1;
  float v;
  if (slot == 0) {
    v = cb[p*22 + i];
  } else {
    int s1 = slot - 1;
    int k = s1 / 3, j = s1 - 3*k;
    float frac = (float)(j+1) * (1.0f/3.0f);
    if (j == 2) frac = 1.0f;
    int base = p*22 + k*2 + i;
    v = cb[base] + (cc2[base] + cd3[base]*frac)*frac;
  }
  dX[idx] = v;
}

__global__ void kInit(const float* __restrict__ ca, const float* __restrict__ Wh,
                      const float* __restrict__ bh, const float* __restrict__ Wz,
                      const float* __restrict__ bz, float* __restrict__ h,
                      float* __restrict__ z) {
  int idx = blockIdx.x*256 + threadIdx.x;       // 262144
  int c = idx & 31, p = idx >> 5;
  float x0 = ca[p*22 + 0], x1 = ca[p*22 + 1];
  h[idx] = fmaf(x0, Wh[c], fmaf(x1, Wh[32+c], bh[c]));
  z[idx] = fmaf(x0, Wz[c], fmaf(x1, Wz[32+c], bz[c]));
}

// initial xrel = relu(z@gWin+gbin), f32 + packed hi B-fragment form
__global__ void kXrel0(const float* __restrict__ z, const float* __restrict__ gWin,
                       const float* __restrict__ gbin, float* __restrict__ xrel,
                       short* __restrict__ xpkH) {
  __shared__ float zl[8][32];
  int t = threadIdx.x, pl = t >> 5, o = t & 31;
  int p = blockIdx.x*8 + pl;
  zl[pl][o] = z[p*32 + o];
  __syncthreads();
  float s = gbin[o];
  #pragma unroll
  for (int i = 0; i < 32; ++i) s = fmaf(zl[pl][i], gWin[i*32 + o], s);
  float xr = fmaxf(s, 0.f);
  xrel[p*32 + o] = xr;
  int b = p >> 9, m = p & 511;
  int c = m >> 5, rr = m & 31;
  int lane = (rr>>3)*16 + (o&15);
  int tt = o >> 4;
  size_t off = (((size_t)(b*16 + c)*2 + tt)*64 + lane)*8 + (rr&7);
  xpkH[off] = (short)bf16h(xr);
}

// ---------------- fused per-stage kernel ----------------
// 512 thr = 8 waves, 16 points, grid 512 (b x ntile, XCD-swizzled).
__global__ __launch_bounds__(512, 4) void kBF(
    const unsigned* __restrict__ awb, const float* __restrict__ ab,
    const float* __restrict__ dX, float* __restrict__ h, float* __restrict__ z,
    float* __restrict__ kh, float* __restrict__ kz,
    float* __restrict__ xrel,
    const short* __restrict__ ApkH, const short* __restrict__ ApkL,
    const short* __restrict__ xpkH, short* __restrict__ xpkHo,
    const short* __restrict__ GpkH, const short* __restrict__ GpkL,
    const short* __restrict__ WpkH, const short* __restrict__ WpkL,
    const float* __restrict__ fbin, const float* __restrict__ fbmid,
    const float* __restrict__ fbout, const float* __restrict__ gbin,
    const float* __restrict__ gbout, int stage, int slot)
{
  __shared__ float scrA[8][16][32];
  __shared__ float bGl[1024];
  __shared__ float HS[16*34], X1[16*34], X2[16*34], PLb[16*34];
  __shared__ float XR[16*36], AG[16*36];
  __shared__ float DHT[32*20];
  __shared__ float DZ[16*33];

  int t = threadIdx.x;
  int pl = t >> 5, o = t & 31;
  int w = t >> 6, l = t & 63;
  int ll = l & 15, lg = l >> 4;
  int bid = blockIdx.x;
  int xcd = bid & 7, sub = (bid >> 3) & 3, b = bid >> 5;
  int ntile = xcd*4 + sub;
  int pgbase = b*512 + ntile*16;
  int pg = pgbase + pl;

  // ---- phase 0: prefetch gWout-hi frags; stage bGl, XR, HS ----
  bf16x8 gHreg[8];
  #pragma unroll
  for (int u = 0; u < 8; ++u)
    gHreg[u] = *(const bf16x8*)(GpkH + ((size_t)(w*8 + u)*64 + l)*8);

  bGl[t] = gbout[t]; bGl[t+512] = gbout[t+512];
  XR[pl*36 + o] = xrel[pg*32 + o];
  {
    float hv = h[pg*32 + o]; float hsv;
    if (stage == 1)      hsv = hv;
    else if (stage == 2) hsv = fmaf(kh[pg*32+o], (1.f/3.f), hv);
    else if (stage == 3) hsv = hv - (1.f/3.f)*kh[pg*32+o] + kh[NPS + pg*32+o];
    else                 hsv = hv + kh[pg*32+o] - kh[NPS + pg*32+o] + kh[2*NPS + pg*32+o];
    HS[pl*34 + o] = hsv;
  }

  // ---- phase A: agg MFMA (A hi+lo, x hi only) ----
  {
    f32x4 acc0 = {0.f,0.f,0.f,0.f}, acc1 = {0.f,0.f,0.f,0.f};
    #pragma unroll
    for (int cc = 0; cc < 2; ++cc) {
      int c = w*2 + cc;
      size_t aoff = ((size_t)(ntile*16 + c)*64 + l)*8;
      bf16x8 aH = *(const bf16x8*)(ApkH + aoff);
      bf16x8 aL = *(const bf16x8*)(ApkL + aoff);
      size_t boff0 = (((size_t)(b*16 + c)*2 + 0)*64 + l)*8;
      size_t boff1 = (((size_t)(b*16 + c)*2 + 1)*64 + l)*8;
      bf16x8 bH0 = *(const bf16x8*)(xpkH + boff0);
      bf16x8 bH1 = *(const bf16x8*)(xpkH + boff1);
      acc0 = __builtin_amdgcn_mfma_f32_16x16x32_bf16(aL, bH0, acc0, 0, 0, 0);
      acc0 = __builtin_amdgcn_mfma_f32_16x16x32_bf16(aH, bH0, acc0, 0, 0, 0);
      acc1 = __builtin_amdgcn_mfma_f32_16x16x32_bf16(aL, bH1, acc1, 0, 0, 0);
      acc1 = __builtin_amdgcn_mfma_f32_16x16x32_bf16(aH, bH1, acc1, 0, 0, 0);
    }
    #pragma unroll
    for (int r = 0; r < 4; ++r) {
      scrA[w][lg*4+r][ll]      = acc0[r];
      scrA[w][lg*4+r][16 + ll] = acc1[r];
    }
  }
  __syncthreads();   // bar1

  // ---- B1: chain L1 | AG reduce | pool part 1 ----
  float plp0 = 0.f, plp1 = 0.f;
  if (w < 2) {
    bf16x8 aH = pack_hi(&HS[ll*34 + lg*8]);
    bf16x8 bH = *(const bf16x8*)(WpkH + (size_t)w*512 + l*8);
    bf16x8 bL = *(const bf16x8*)(WpkL + (size_t)w*512 + l*8);
    f32x4 acc = {0.f,0.f,0.f,0.f};
    acc = __builtin_amdgcn_mfma_f32_16x16x32_bf16(aH, bL, acc, 0, 0, 0);
    acc = __builtin_amdgcn_mfma_f32_16x16x32_bf16(aH, bH, acc, 0, 0, 0);
    int col = w*16 + ll;
    float bb = fbin[col];
    #pragma unroll
    for (int r = 0; r < 4; ++r) X1[(lg*4+r)*34 + col] = fmaxf(acc[r] + bb, 0.f);
  } else if (w < 4) {
    int base = (t - 128)*4;
    #pragma unroll
    for (int jj = 0; jj < 4; ++jj) {
      int s = base + jj; int sp = s>>5, so = s&31;
      float v = 0.f;
      #pragma unroll
      for (int ww = 0; ww < 8; ++ww) v += scrA[ww][sp][so];
      AG[sp*36 + so] = v;
    }
  } else {
    #pragma unroll
    for (int half = 0; half < 2; ++half) {
      int s = (t - 256) + half*256;
      int sp = s>>5, so = s&31;
      int nn = ntile*16 + sp;
      const unsigned* awp = awb + (size_t)nn*1024 + so;
      const float2* xr2 = (const float2*)&XR[sp*36];
      float acc = 0.f;
      #pragma unroll
      for (int q = 0; q < 16; ++q) {
        unsigned u = awp[q*32];
        float2 xv = xr2[q];
        acc = fmaf(xv.x, __uint_as_float(u << 16), acc);
        acc = fmaf(xv.y, __uint_as_float(u & 0xffff0000u), acc);
      }
      if (half == 0) plp0 = acc; else plp1 = acc;
    }
  }
  __syncthreads();   // bar2

  // ---- B2: chain L2 | pool part 2 + PL write ----
  if (w < 2) {
    bf16x8 aH = pack_hi(&X1[ll*34 + lg*8]);
    bf16x8 bH = *(const bf16x8*)(WpkH + (size_t)(2+w)*512 + l*8);
    bf16x8 bL = *(const bf16x8*)(WpkL + (size_t)(2+w)*512 + l*8);
    f32x4 acc = {0.f,0.f,0.f,0.f};
    acc = __builtin_amdgcn_mfma_f32_16x16x32_bf16(aH, bL, acc, 0, 0, 0);
    acc = __builtin_amdgcn_mfma_f32_16x16x32_bf16(aH, bH, acc, 0, 0, 0);
    int col = w*16 + ll;
    float bb = fbmid[col];
    #pragma unroll
    for (int r = 0; r < 4; ++r) X2[(lg*4+r)*34 + col] = fmaxf(acc[r] + bb, 0.f);
  } else if (w >= 4) {
    #pragma unroll
    for (int half = 0; half < 2; ++half) {
      int s = (t - 256) + half*256;
      int sp = s>>5, so = s&31;
      int nn = ntile*16 + sp;
      const unsigned* awp = awb + (size_t)nn*1024 + 512 + so;
      const float2* ag2 = (const float2*)&AG[sp*36];
      float acc = (half == 0) ? plp0 : plp1;
      #pragma unroll
      for (int q = 0; q < 16; ++q) {
        unsigned u = awp[q*32];
        float2 av = ag2[q];
        acc = fmaf(av.x, __uint_as_float(u << 16), acc);
        acc = fmaf(av.y, __uint_as_float(u & 0xffff0000u), acc);
      }
      PLb[sp*34 + so] = acc + ab[nn*32 + so];
    }
  }
  __syncthreads();   // bar3

  // ---- D: fWout + tanh + dh -> DHT (waves 0,1) ----
  if (w < 2) {
    bf16x8 aH = pack_hi(&X2[ll*34 + lg*8]);
    float vf[2][4];
    #pragma unroll
    for (int e = 0; e < 2; ++e) {
      int T = 2*w + e;
      bf16x8 bH = *(const bf16x8*)(WpkH + (size_t)(4+T)*512 + l*8);
      bf16x8 bL = *(const bf16x8*)(WpkL + (size_t)(4+T)*512 + l*8);
      f32x4 acc = {0.f,0.f,0.f,0.f};
      acc = __builtin_amdgcn_mfma_f32_16x16x32_bf16(aH, bL, acc, 0, 0, 0);
      acc = __builtin_amdgcn_mfma_f32_16x16x32_bf16(aH, bH, acc, 0, 0, 0);
      int col = T*16 + ll;
      float bb = fbout[col];
      #pragma unroll
      for (int r = 0; r < 4; ++r) vf[e][r] = tanh_fast(acc[r] + bb);
    }
    float2 dxv[4];
    #pragma unroll
    for (int r = 0; r < 4; ++r)
      dxv[r] = *(const float2*)&dX[(size_t)slot*16384 + (size_t)(pgbase + lg*4 + r)*2];
    #pragma unroll
    for (int e = 0; e < 2; ++e) {
      int T = 2*w + e;
      float vo[4];
      #pragma unroll
      for (int r = 0; r < 4; ++r) vo[r] = __shfl_xor(vf[e][r], 1);
      if (!(l & 1)) {
        int hh = T*8 + (ll>>1);
        float4 dv;
        dv.x = vf[e][0]*dxv[0].x + vo[0]*dxv[0].y;
        dv.y = vf[e][1]*dxv[1].x + vo[1]*dxv[1].y;
        dv.z = vf[e][2]*dxv[2].x + vo[2]*dxv[2].y;
        dv.w = vf[e][3]*dxv[3].x + vo[3]*dxv[3].y;
        *(float4*)&DHT[hh*20 + lg*4] = dv;
      }
    }
  }
  __syncthreads();   // bar4

  // ---- E: vg = tanh(PL@gWout + gbout), dz partial + shfl reduce ----
  {
    bf16x8 paH = pack_hi(&PLb[ll*34 + lg*8]);
    bf16x8 gLreg[8];
    #pragma unroll
    for (int u = 0; u < 8; ++u)
      gLreg[u] = *(const bf16x8*)(GpkL + ((size_t)(w*8 + u)*64 + l)*8);
    float p[4][4] = {{0.f,0.f,0.f,0.f},{0.f,0.f,0.f,0.f},{0.f,0.f,0.f,0.f},{0.f,0.f,0.f,0.f}};
    #pragma unroll
    for (int u = 0; u < 8; ++u) {
      f32x4 acc = {0.f,0.f,0.f,0.f};
      acc = __builtin_amdgcn_mfma_f32_16x16x32_bf16(paH, gLreg[u], acc, 0, 0, 0);
      acc = __builtin_amdgcn_mfma_f32_16x16x32_bf16(paH, gHreg[u], acc, 0, 0, 0);
      int tile = w*8 + u;
      int col = tile*16 + ll, oo = col & 31;
      float gb = bGl[col];
      float4 dh4 = *(const float4*)&DHT[oo*20 + lg*4];
      int h2 = u >> 1;
      float da[4] = {dh4.x, dh4.y, dh4.z, dh4.w};
      #pragma unroll
      for (int r = 0; r < 4; ++r) {
        float tv = tanh_fast(acc[r] + gb);
        p[r][h2] = fmaf(tv, da[r], p[r][h2]);
      }
    }
    #pragma unroll
    for (int r = 0; r < 4; ++r) {
      #pragma unroll
      for (int h2 = 0; h2 < 4; ++h2) {
        float v = p[r][h2];
        v += __shfl_xor(v, 1);
        v += __shfl_xor(v, 2);
        v += __shfl_xor(v, 4);
        v += __shfl_xor(v, 8);
        if (ll == r*4 + h2) DZ[(lg*4 + r)*33 + w*4 + h2] = v;
      }
    }
  }
  __syncthreads();   // bar5

  // ---- F: RK bookkeeping (h & z), z_next -> X1 ----
  {
    float dzv = DZ[pl*33 + o];
    float dhv = DHT[o*20 + pl];
    if (stage < 4) {
      kh[(size_t)(stage-1)*NPS + pg*32 + o] = dhv;
    } else {
      float hv = h[pg*32+o];
      float k1 = kh[pg*32+o], k2 = kh[NPS+pg*32+o], k3 = kh[2*NPS+pg*32+o];
      h[pg*32+o] = hv + 0.125f*(k1 + 3.f*(k2 + k3) + dhv);
    }
    float zv = z[pg*32 + o];
    float znv;
    if (stage == 1) {
      kz[pg*32+o] = dzv;
      znv = fmaf(dzv, (1.f/3.f), zv);
    } else if (stage == 2) {
      kz[NPS + pg*32+o] = dzv;
      znv = zv - (1.f/3.f)*kz[pg*32+o] + dzv;
    } else if (stage == 3) {
      kz[2*NPS + pg*32+o] = dzv;
      znv = zv + kz[pg*32+o] - kz[NPS+pg*32+o] + dzv;
    } else {
      float k1 = kz[pg*32+o], k2 = kz[NPS+pg*32+o], k3 = kz[2*NPS+pg*32+o];
      znv = zv + 0.125f*(k1 + 3.f*(k2 + k3) + dzv);
      z[pg*32+o] = znv;
    }
    X1[pl*34 + o] = znv;   // reuse X1 as z_next
  }
  __syncthreads();   // bar6

  // ---- G: xrel_next = relu(z_next@gWin+gbin) via MFMA; store f32 + packed hi ----
  if (w < 2) {
    bf16x8 aH = pack_hi(&X1[ll*34 + lg*8]);
    bf16x8 bH = *(const bf16x8*)(WpkH + (size_t)(8+w)*512 + l*8);
    bf16x8 bL = *(const bf16x8*)(WpkL + (size_t)(8+w)*512 + l*8);
    f32x4 acc = {0.f,0.f,0.f,0.f};
    acc = __builtin_amdgcn_mfma_f32_16x16x32_bf16(aH, bL, acc, 0, 0, 0);
    acc = __builtin_amdgcn_mfma_f32_16x16x32_bf16(aH, bH, acc, 0, 0, 0);
    int col = w*16 + ll;
    float bb = gbin[col];
    int hp = ntile & 1, cch = ntile >> 1;
    #pragma unroll
    for (int r = 0; r < 4; ++r) {
      float xr = fmaxf(acc[r] + bb, 0.f);
      int row = lg*4 + r;
      xrel[(size_t)(pgbase + row)*32 + col] = xr;
      int rr = hp*16 + row;
      size_t off = (((size_t)(b*16 + cch)*2 + w)*64 + ((rr>>3)*16 + ll))*8 + (rr&7);
      xpkHo[off] = (short)bf16h(xr);
    }
  }
}

// out[b,0,n,o] = sum_h z[b,n,h]*convW[o,h] + convb[o]
__global__ void kOut(const float* __restrict__ z, const float* __restrict__ convW,
                     const float* __restrict__ convb, float* __restrict__ out) {
  int idx = blockIdx.x*256 + threadIdx.x;   // 98304
  int o = idx % 12, p = idx / 12;
  float s = convb[o];
  #pragma unroll
  for (int hh = 0; hh < 32; ++hh) s = fmaf(z[p*32 + hh], convW[o*32 + hh], s);
  out[idx] = s;
}

extern "C" void kernel_launch(void* const* d_in, const int* in_sizes, int n_in,
                              void* d_out, int out_size, void* d_ws, size_t ws_size,
                              hipStream_t stream) {
  (void)in_sizes; (void)n_in; (void)out_size; (void)ws_size;
  const float* ca     = (const float*)d_in[1];
  const float* cb     = (const float*)d_in[2];
  const float* cc2    = (const float*)d_in[3];
  const float* cd3    = (const float*)d_in[4];
  const float* Wh     = (const float*)d_in[5];
  const float* bh     = (const float*)d_in[6];
  const float* Wz     = (const float*)d_in[7];
  const float* bz     = (const float*)d_in[8];
  const float* fWin   = (const float*)d_in[9];
  const float* fbin   = (const float*)d_in[10];
  const float* fWmid  = (const float*)d_in[11];
  const float* fbmid  = (const float*)d_in[12];
  const float* fWout  = (const float*)d_in[13];
  const float* fbout  = (const float*)d_in[14];
  const float* gWin   = (const float*)d_in[15];
  const float* gbin   = (const float*)d_in[16];
  const float* gE     = (const float*)d_in[17];
  const float* gWpool = (const float*)d_in[18];
  const float* gbpool = (const float*)d_in[19];
  const float* gWout  = (const float*)d_in[20];
  const float* gbout  = (const float*)d_in[21];
  const float* convW  = (const float*)d_in[22];
  const float* convb  = (const float*)d_in[23];
  float* out = (float*)d_out;

  float* wsf  = (float*)d_ws;
  unsigned* awb = (unsigned*)wsf;            // 524288 uints
  float* wAb  = wsf + 524288;                // 16384
  float* wDX  = wAb + 16384;                 // 557056
  float* wH   = wDX + 557056;                // 262144
  float* wZ   = wH + 262144;                 // 262144
  float* wKh  = wZ + 262144;                 // 786432
  float* wKz  = wKh + 786432;                // 786432
  float* wXr  = wKz + 786432;                // 262144
  short* ApkH = (short*)(wXr + 262144);      // 262144 shorts each below
  short* ApkL = ApkH + 262144;
  short* xp0H = ApkL + 262144;
  short* xp1H = xp0H + 262144;
  short* GpkH = xp1H + 262144;               // 32768
  short* GpkL = GpkH + 32768;                // 32768
  short* WpkH = GpkL + 32768;                // 5120
  short* WpkL = WpkH + 5120;                 // 5120

  kA_softmax<<<512, 256, 0, stream>>>(gE, ApkH, ApkL);
  kAwB<<<512, 256, 0, stream>>>(gE, gWpool, gbpool, awb, wAb);
  kPackGW<<<128, 256, 0, stream>>>(gWout, GpkH, GpkL);
  kPackW<<<20, 256, 0, stream>>>(fWin, fWmid, fWout, gWin, WpkH, WpkL);
  kDX<<<2176, 256, 0, stream>>>(cb, cc2, cd3, wDX);
  kInit<<<1024, 256, 0, stream>>>(ca, Wh, bh, Wz, bz, wH, wZ);
  kXrel0<<<1024, 256, 0, stream>>>(wZ, gWin, gbin, wXr, xp0H);

  for (int ss = 0; ss < 44; ++ss) {
    int stage = (ss & 3) + 1;
    int step = ss >> 2;
    int slot = (ss == 0) ? 0 : (3*step + (ss & 3));
    const short* xiH = (ss & 1) ? xp1H : xp0H;
    short* xoH = (ss & 1) ? xp0H : xp1H;
    kBF<<<512, 512, 0, stream>>>(awb, wAb, wDX, wH, wZ, wKh, wKz, wXr,
                                 ApkH, ApkL, xiH, xoH, GpkH, GpkL,
                                 WpkH, WpkL, fbin, fbmid, fbout, gbin, gbout,
                                 stage, slot);
  }
  kOut<<<384, 256, 0, stream>>>(wZ, convW, convb, out);
}